// Round 15
// baseline (573.761 us; speedup 1.0000x reference)
//
#include <hip/hip_runtime.h>

#define HIDN 2048
#define NHEAD 16
#define HDIM 128
#define FFDIM 8192
#define SEQLEN 2048

typedef __attribute__((ext_vector_type(8))) __bf16 bf16x8;
typedef __attribute__((ext_vector_type(4))) float f32x4;
typedef __attribute__((ext_vector_type(4))) unsigned short u16x4;
typedef __attribute__((ext_vector_type(8))) unsigned short u16x8;

__device__ __forceinline__ unsigned short f2bfu(float f) {
    unsigned int u = __float_as_uint(f);
    unsigned int r = u + 0x7fffu + ((u >> 16) & 1u);
    return (unsigned short)(r >> 16);
}
__device__ __forceinline__ float bfu2f(unsigned short u) {
    return __uint_as_float(((unsigned int)u) << 16);
}

__device__ __forceinline__ void gload16(const void* g, void* l) {
    __builtin_amdgcn_global_load_lds(
        (const __attribute__((address_space(1))) unsigned int*)g,
        (__attribute__((address_space(3))) unsigned int*)l,
        16, 0, 0);
}

__device__ __forceinline__ void conv_groups(const float* __restrict__ src,
                                            unsigned short* __restrict__ dst,
                                            int i0, int stride, int n8) {
    for (int i = i0; i < n8; i += stride) {
        float4 a = ((const float4*)src)[i * 2];
        float4 b = ((const float4*)src)[i * 2 + 1];
        u16x8 v;
        v[0] = f2bfu(a.x); v[1] = f2bfu(a.y); v[2] = f2bfu(a.z); v[3] = f2bfu(a.w);
        v[4] = f2bfu(b.x); v[5] = f2bfu(b.y); v[6] = f2bfu(b.z); v[7] = f2bfu(b.w);
        *(u16x8*)(dst + (size_t)i * 8) = v;
    }
}

__device__ __forceinline__ void conv_tail3(const float* __restrict__ s0,
                                           const float* __restrict__ s1,
                                           const float* __restrict__ s2,
                                           unsigned short* __restrict__ dst,
                                           int i0, int stride, int nmat) {
    const int FF8 = FFDIM * HIDN / 8;
    const int tot = nmat * FF8;
    for (int i = i0; i < tot; i += stride) {
        int m = i >> 21;
        int li = i & (FF8 - 1);
        const float* s = (m == 0) ? s0 : (m == 1) ? s1 : s2;
        float4 a = ((const float4*)s)[li * 2];
        float4 b = ((const float4*)s)[li * 2 + 1];
        u16x8 v;
        v[0] = f2bfu(a.x); v[1] = f2bfu(a.y); v[2] = f2bfu(a.z); v[3] = f2bfu(a.w);
        v[4] = f2bfu(b.x); v[5] = f2bfu(b.y); v[6] = f2bfu(b.z); v[7] = f2bfu(b.w);
        *(u16x8*)(dst + (size_t)i * 8) = v;
    }
}

// ---------------- fp32 -> bf16 weight conversion (standalone) ----------------
__global__ __launch_bounds__(256)
void conv_f32_bf16(const float* __restrict__ src, unsigned short* __restrict__ dst) {
    int i = blockIdx.x * 256 + threadIdx.x;
    conv_groups(src, dst, i, 1 << 30, i + 1);
}

__global__ __launch_bounds__(256)
void conv3_f32_bf16(const float* __restrict__ s0, const float* __restrict__ s1,
                    const float* __restrict__ s2, unsigned short* __restrict__ dst) {
    int i = blockIdx.x * 256 + threadIdx.x;
    int m = i >> 19;
    int li = i & ((1 << 19) - 1);
    const float* s = (m == 0) ? s0 : (m == 1) ? s1 : s2;
    float4 a = ((const float4*)s)[li * 2];
    float4 b = ((const float4*)s)[li * 2 + 1];
    u16x8 v;
    v[0] = f2bfu(a.x); v[1] = f2bfu(a.y); v[2] = f2bfu(a.z); v[3] = f2bfu(a.w);
    v[4] = f2bfu(b.x); v[5] = f2bfu(b.y); v[6] = f2bfu(b.z); v[7] = f2bfu(b.w);
    *(u16x8*)(dst + (size_t)i * 8) = v;
}

// ---------------- LayerNorm (fp32 in) -> bf16 out ----------------
__global__ __launch_bounds__(256)
void ln_bf16(const float* __restrict__ x, const float* __restrict__ w,
             const float* __restrict__ b, unsigned short* __restrict__ out) {
    const int row = blockIdx.x;
    const int tid = threadIdx.x;
    const float* xr = x + (size_t)row * HIDN;
    float4 v0 = ((const float4*)xr)[tid];
    float4 v1 = ((const float4*)xr)[tid + 256];
    float s = v0.x + v0.y + v0.z + v0.w + v1.x + v1.y + v1.z + v1.w;
    float q = v0.x*v0.x + v0.y*v0.y + v0.z*v0.z + v0.w*v0.w
            + v1.x*v1.x + v1.y*v1.y + v1.z*v1.z + v1.w*v1.w;
    for (int o = 32; o > 0; o >>= 1) {
        s += __shfl_down(s, o, 64);
        q += __shfl_down(q, o, 64);
    }
    __shared__ float red[8];
    const int wid = tid >> 6;
    if ((tid & 63) == 0) { red[wid] = s; red[4 + wid] = q; }
    __syncthreads();
    float st = red[0] + red[1] + red[2] + red[3];
    float qt = red[4] + red[5] + red[6] + red[7];
    float mu = st * (1.0f / HIDN);
    float var = qt * (1.0f / HIDN) - mu * mu;
    float rs = rsqrtf(var + 1e-5f);
    unsigned short* orow = out + (size_t)row * HIDN;
    int i0 = tid * 4, i1 = (tid + 256) * 4;
    orow[i0 + 0] = f2bfu((v0.x - mu) * rs * w[i0 + 0] + b[i0 + 0]);
    orow[i0 + 1] = f2bfu((v0.y - mu) * rs * w[i0 + 1] + b[i0 + 1]);
    orow[i0 + 2] = f2bfu((v0.z - mu) * rs * w[i0 + 2] + b[i0 + 2]);
    orow[i0 + 3] = f2bfu((v0.w - mu) * rs * w[i0 + 3] + b[i0 + 3]);
    orow[i1 + 0] = f2bfu((v1.x - mu) * rs * w[i1 + 0] + b[i1 + 0]);
    orow[i1 + 1] = f2bfu((v1.y - mu) * rs * w[i1 + 1] + b[i1 + 1]);
    orow[i1 + 2] = f2bfu((v1.z - mu) * rs * w[i1 + 2] + b[i1 + 2]);
    orow[i1 + 3] = f2bfu((v1.w - mu) * rs * w[i1 + 3] + b[i1 + 3]);
}

// ---------------- WO combine + residual + LN2, one block per row ----------------
__global__ __launch_bounds__(256)
void wo_ln(const unsigned short* __restrict__ part, const float* __restrict__ h,
           const float* __restrict__ bo, const float* __restrict__ w,
           const float* __restrict__ b, float* __restrict__ out,
           unsigned short* __restrict__ ybf) {
    const int row = blockIdx.x;
    const int tid = threadIdx.x;
    const int c0 = tid * 4, c1 = (tid + 256) * 4;
    float4 o0 = ((const float4*)(h + (size_t)row * HIDN))[tid];
    float4 o1 = ((const float4*)(h + (size_t)row * HIDN))[tid + 256];
    o0.x += bo[c0]; o0.y += bo[c0 + 1]; o0.z += bo[c0 + 2]; o0.w += bo[c0 + 3];
    o1.x += bo[c1]; o1.y += bo[c1 + 1]; o1.z += bo[c1 + 2]; o1.w += bo[c1 + 3];
#pragma unroll
    for (int sk = 0; sk < 4; ++sk) {
        const unsigned short* pr = part + (size_t)sk * 4194304 + (size_t)row * HIDN;
        u16x4 p0 = *(const u16x4*)(pr + c0);
        u16x4 p1 = *(const u16x4*)(pr + c1);
        o0.x += bfu2f(p0[0]); o0.y += bfu2f(p0[1]); o0.z += bfu2f(p0[2]); o0.w += bfu2f(p0[3]);
        o1.x += bfu2f(p1[0]); o1.y += bfu2f(p1[1]); o1.z += bfu2f(p1[2]); o1.w += bfu2f(p1[3]);
    }
    ((float4*)(out + (size_t)row * HIDN))[tid] = o0;
    ((float4*)(out + (size_t)row * HIDN))[tid + 256] = o1;
    float s = o0.x + o0.y + o0.z + o0.w + o1.x + o1.y + o1.z + o1.w;
    float q = o0.x*o0.x + o0.y*o0.y + o0.z*o0.z + o0.w*o0.w
            + o1.x*o1.x + o1.y*o1.y + o1.z*o1.z + o1.w*o1.w;
    for (int o = 32; o > 0; o >>= 1) {
        s += __shfl_down(s, o, 64);
        q += __shfl_down(q, o, 64);
    }
    __shared__ float red[8];
    const int wid = tid >> 6;
    if ((tid & 63) == 0) { red[wid] = s; red[4 + wid] = q; }
    __syncthreads();
    float st = red[0] + red[1] + red[2] + red[3];
    float qt = red[4] + red[5] + red[6] + red[7];
    float mu = st * (1.0f / HIDN);
    float var = qt * (1.0f / HIDN) - mu * mu;
    float rs = rsqrtf(var + 1e-5f);
    unsigned short* yr = ybf + (size_t)row * HIDN;
    yr[c0 + 0] = f2bfu((o0.x - mu) * rs * w[c0 + 0] + b[c0 + 0]);
    yr[c0 + 1] = f2bfu((o0.y - mu) * rs * w[c0 + 1] + b[c0 + 1]);
    yr[c0 + 2] = f2bfu((o0.z - mu) * rs * w[c0 + 2] + b[c0 + 2]);
    yr[c0 + 3] = f2bfu((o0.w - mu) * rs * w[c0 + 3] + b[c0 + 3]);
    yr[c1 + 0] = f2bfu((o1.x - mu) * rs * w[c1 + 0] + b[c1 + 0]);
    yr[c1 + 1] = f2bfu((o1.y - mu) * rs * w[c1 + 1] + b[c1 + 1]);
    yr[c1 + 2] = f2bfu((o1.z - mu) * rs * w[c1 + 2] + b[c1 + 2]);
    yr[c1 + 3] = f2bfu((o1.w - mu) * rs * w[c1 + 3] + b[c1 + 3]);
}

// ---------------- RoPE in-place on qk buffer [S][4096] ----------------
__global__ __launch_bounds__(256)
void rope_kernel(unsigned short* __restrict__ qk, const int* __restrict__ tsl) {
    int id = blockIdx.x * 256 + threadIdx.x;
    int p  = id & 63;
    int hh = (id >> 6) & 31;
    int s  = id >> 11;
    int off = tsl[0] - SEQLEN;
    float inv = exp2f((float)p * -0.20762050593f);
    float ang = (float)(s + off) * inv;
    float c, sn;
    __sincosf(ang, &sn, &c);
    size_t base = (size_t)s * 4096 + hh * 128 + p;
    float x1 = bfu2f(qk[base]);
    float x2 = bfu2f(qk[base + 64]);
    qk[base]      = f2bfu(x1 * c - x2 * sn);
    qk[base + 64] = f2bfu(x2 * c + x1 * sn);
}

// ======= 256x256 8-phase GEMM (R8 schedule) for QKV + tail-conv blocks =======
#define BAR __builtin_amdgcn_s_barrier()
#define VM4 asm volatile("s_waitcnt vmcnt(4)" ::: "memory")
#define VM0 asm volatile("s_waitcnt vmcnt(0)" ::: "memory")

#define STAGE_A(tile, h) { const int k0_ = k_start + (tile) * 64;                      \
  _Pragma("unroll") for (int i_ = 0; i_ < 2; ++i_) {                                   \
    int d_ = (h) * 16384 + i_ * 8192 + tid * 16;                                       \
    int r_ = d_ >> 7;                                                                  \
    int cb_ = (d_ & 127) ^ ((r_ & 7) << 4);                                            \
    gload16((const char*)Ab + ((size_t)(brow + r_) * lda + k0_) * 2 + cb_,             \
            smem + ((tile) & 1) * 65536 + (h) * 16384 + i_ * 8192 + w * 1024); } }

#define STAGE_B(tile, h) { const int k0_ = k_start + (tile) * 64;                      \
  _Pragma("unroll") for (int i_ = 0; i_ < 2; ++i_) {                                   \
    int d_ = (h) * 16384 + i_ * 8192 + tid * 16;                                       \
    int r_ = d_ >> 7;                                                                  \
    int cb_ = (d_ & 127) ^ ((r_ & 7) << 4);                                            \
    gload16((const char*)Bb + ((size_t)(bcol + r_) * ldb + k0_) * 2 + cb_,             \
            smem + ((tile) & 1) * 65536 + 32768 + (h) * 16384 + i_ * 8192 + w * 1024); } }

#define LDB(BO)                                                                        \
  _Pragma("unroll") for (int n_ = 0; n_ < 4; ++n_)                                     \
  _Pragma("unroll") for (int kk_ = 0; kk_ < 2; ++kk_)                                  \
    bF[n_][kk_] = *(const bf16x8*)(smem + (BO) + bbase + n_ * 2048 + colb[kk_]);

#define LDA2(BO, MP)                                                                   \
  _Pragma("unroll") for (int dm_ = 0; dm_ < 2; ++dm_)                                  \
  _Pragma("unroll") for (int kk_ = 0; kk_ < 2; ++kk_)                                  \
    aF[dm_][kk_] = *(const bf16x8*)(smem + (BO) + abase + ((MP) * 2 + dm_) * 2048 + colb[kk_]);

#define MM(MP)                                                                         \
  __builtin_amdgcn_s_setprio(1);                                                       \
  _Pragma("unroll") for (int dm_ = 0; dm_ < 2; ++dm_)                                  \
  _Pragma("unroll") for (int n_ = 0; n_ < 4; ++n_)                                     \
  _Pragma("unroll") for (int kk_ = 0; kk_ < 2; ++kk_)                                  \
    acc[(MP) * 2 + dm_][n_] = __builtin_amdgcn_mfma_f32_16x16x32_bf16(                 \
        aF[dm_][kk_], bF[n_][kk_], acc[(MP) * 2 + dm_][n_], 0, 0, 0);                  \
  __builtin_amdgcn_s_setprio(0);

// EPI0 only: QKV fused with V-transpose + biases; tail blocks convert wo
__global__ __launch_bounds__(512, 1)
void gemm256_qkv(const unsigned short* __restrict__ Ab, int lda,
                 const unsigned short* __restrict__ Bb, int ldb,
                 int k_len, int nbx,
                 const float* __restrict__ bias0, const float* __restrict__ bias1,
                 const float* __restrict__ bias2,
                 unsigned short* __restrict__ outB, unsigned short* __restrict__ outV,
                 int ngemm, const float* __restrict__ csrc,
                 unsigned short* __restrict__ cdst, int conv_n8) {
    extern __shared__ char smem[];   // 131072 bytes
    const int tid = threadIdx.x;

    if ((int)blockIdx.x >= ngemm) {
        conv_groups(csrc, cdst, (blockIdx.x - ngemm) * 512 + tid,
                    (gridDim.x - ngemm) * 512, conv_n8);
        return;
    }

    const int w = tid >> 6, lane = tid & 63;
    const int lr = lane & 15, lg = lane >> 4;
    const int wrow = (w >> 2) * 128;
    const int wc = w & 3;

    const int cpx = nbx >> 3;
    const int xcd = blockIdx.x & 7;
    const int loc = blockIdx.x >> 3;
    const int bx = xcd * cpx + loc % cpx;
    const int by = loc / cpx;
    const int brow = by * 256, bcol = bx * 256;
    const int k_start = 0;

    const int xorv = (lr & 7) << 4;
    int colb[2];
    colb[0] = (lg * 16) ^ xorv;
    colb[1] = (64 + lg * 16) ^ xorv;
    const int abase = (wrow + lr) * 128;
    const int bbase = 32768 + (wc * 64 + lr) * 128;

    f32x4 acc[8][4];
#pragma unroll
    for (int m = 0; m < 8; ++m)
#pragma unroll
        for (int n = 0; n < 4; ++n) acc[m][n] = (f32x4){0.f, 0.f, 0.f, 0.f};

    bf16x8 bF[4][2], aF[2][2];

    const int NT = k_len >> 6;
    const int NIT = NT >> 1;

    STAGE_A(0, 0); STAGE_A(0, 1); STAGE_B(0, 0); STAGE_B(0, 1);
    STAGE_B(1, 0); STAGE_B(1, 1);
    VM4; BAR;

    for (int it = 0; it < NIT; ++it) {
        const int T = 2 * it;
        const bool s2 = (T + 2) < NT, s3 = (T + 3) < NT;
        LDB(0); LDA2(0, 0); STAGE_A(T + 1, 0); MM(0); BAR;
        LDA2(0, 1); STAGE_A(T + 1, 1); MM(1); BAR;
        LDA2(0, 2); if (s2) STAGE_B(T + 2, 0); MM(2); BAR;
        LDA2(0, 3); if (s2) STAGE_B(T + 2, 1); MM(3);
        if (s2) { VM4; } else { VM0; }
        BAR;
        LDB(65536); LDA2(65536, 0); if (s2) STAGE_A(T + 2, 0); MM(0); BAR;
        LDA2(65536, 1); if (s2) STAGE_A(T + 2, 1); MM(1); BAR;
        LDA2(65536, 2); if (s3) STAGE_B(T + 3, 0); MM(2); BAR;
        LDA2(65536, 3); if (s3) STAGE_B(T + 3, 1); MM(3);
        if (s3) { VM4; } else { VM0; }
        BAR;
    }

    char* sw = smem + w * 16384;
    const bool vblk = bcol >= 4096;

    if (!vblk) {
#pragma unroll
        for (int n = 0; n < 4; ++n) {
            const int col = bcol + wc * 64 + n * 16 + lr;
            float bv = (col < 2048) ? bias0[col] : bias1[col - 2048];
#pragma unroll
            for (int m = 0; m < 8; ++m)
#pragma unroll
                for (int j = 0; j < 4; ++j) {
                    const int r = m * 16 + lg * 4 + j;
                    const int cb = ((n * 16 + lr) * 2) ^ ((r & 7) << 4);
                    *(unsigned short*)(sw + r * 128 + cb) = f2bfu(acc[m][n][j] + bv);
                }
        }
        const int rl = lane >> 3, cl = lane & 7;
#pragma unroll
        for (int it2 = 0; it2 < 16; ++it2) {
            const int r = it2 * 8 + rl;
            const int cb = (cl * 16) ^ ((r & 7) << 4);
            u16x8 val = *(const u16x8*)(sw + r * 128 + cb);
            *(u16x8*)(outB + (size_t)(brow + wrow + r) * 4096 + bcol + wc * 64 + cl * 8) = val;
        }
    } else {
#pragma unroll
        for (int n = 0; n < 4; ++n) {
            const int c = n * 16 + lr;
            const float bv = bias2[bcol - 4096 + wc * 64 + c];
            const int cx = (c & 7) << 4;
#pragma unroll
            for (int m = 0; m < 8; ++m) {
                const int r0 = m * 16 + lg * 4;
                u16x4 pk;
#pragma unroll
                for (int j = 0; j < 4; ++j) pk[j] = f2bfu(acc[m][n][j] + bv);
                *(u16x4*)(sw + c * 256 + ((r0 * 2) ^ cx)) = pk;
            }
        }
        const int cg = lane >> 4, rl2 = lane & 15;
#pragma unroll
        for (int it2 = 0; it2 < 16; ++it2) {
            const int c = it2 * 4 + cg;
            const int rb = (rl2 * 16) ^ ((c & 7) << 4);
            u16x8 val = *(const u16x8*)(sw + c * 256 + rb);
            const int d = bcol - 4096 + wc * 64 + c;
            *(u16x8*)(outV + (size_t)d * SEQLEN + brow + wrow + rl2 * 8) = val;
        }
    }
}

// ======= 128x256 GEMM, single-buffered 48KB LDS, 2-3 blocks/CU =======
// EPI 1: outB = bf16(acc); EPI 3: outB = bf16(silu(prev)*acc) in-place;
// EPI 4: outB[ky*4M + row*ldc+col] = bf16(acc) (split-K partial)
#define STG128 { const int k0_ = k_start + T1 * 64;                                    \
  _Pragma("unroll") for (int i_ = 0; i_ < 2; ++i_) {                                   \
    int d_ = i_ * 8192 + tid * 16;                                                     \
    int r_ = d_ >> 7;                                                                  \
    int cb_ = (d_ & 127) ^ ((r_ & 7) << 4);                                            \
    gload16((const char*)Ab + ((size_t)(brow + r_) * lda + k0_) * 2 + cb_,             \
            smem + i_ * 8192 + w * 1024); }                                            \
  _Pragma("unroll") for (int i_ = 0; i_ < 4; ++i_) {                                   \
    int d_ = i_ * 8192 + tid * 16;                                                     \
    int r_ = d_ >> 7;                                                                  \
    int cb_ = (d_ & 127) ^ ((r_ & 7) << 4);                                            \
    gload16((const char*)Bb + ((size_t)(bcol + r_) * ldb + k0_) * 2 + cb_,             \
            smem + 16384 + i_ * 8192 + w * 1024); } }

template<int EPI>
__global__ __launch_bounds__(512)
void gemm128(const unsigned short* __restrict__ Ab, int lda,
             const unsigned short* __restrict__ Bb, int ldb,
             int k_len, int nbx, int ldc,
             unsigned short* __restrict__ outB) {
    extern __shared__ char smem[];   // 49152: A [0,16K), B [16K,48K)
    const int tid = threadIdx.x;
    const int w = tid >> 6, lane = tid & 63;
    const int lr = lane & 15, lg = lane >> 4;
    const int wrow = (w >> 2) * 64;    // 2 wave-rows of 64
    const int wc = w & 3;              // 4 wave-cols of 64

    const int cpx = nbx >> 3;
    const int xcd = blockIdx.x & 7;
    const int loc = blockIdx.x >> 3;
    const int bx = xcd * cpx + loc % cpx;
    const int by = loc / cpx;
    const int brow = by * 128, bcol = bx * 256;
    const int k_start = blockIdx.y * k_len;

    const int xorv = (lr & 7) << 4;
    int colb[2];
    colb[0] = (lg * 16) ^ xorv;
    colb[1] = (64 + lg * 16) ^ xorv;
    const int abase = (wrow + lr) * 128;
    const int bbase = 16384 + (wc * 64 + lr) * 128;

    f32x4 acc[4][4];
#pragma unroll
    for (int m = 0; m < 4; ++m)
#pragma unroll
        for (int n = 0; n < 4; ++n) acc[m][n] = (f32x4){0.f, 0.f, 0.f, 0.f};

    bf16x8 bF[4][2], aF[4][2];

    const int NT = k_len >> 6;

    { const int T1 = 0; STG128; }
    for (int T = 0; T < NT; ++T) {
        VM0; BAR;
        // compute tile T from LDS
#pragma unroll
        for (int n = 0; n < 4; ++n)
#pragma unroll
            for (int kk = 0; kk < 2; ++kk)
                bF[n][kk] = *(const bf16x8*)(smem + bbase + n * 2048 + colb[kk]);
#pragma unroll
        for (int m = 0; m < 4; ++m)
#pragma unroll
            for (int kk = 0; kk < 2; ++kk)
                aF[m][kk] = *(const bf16x8*)(smem + abase + m * 2048 + colb[kk]);
        __builtin_amdgcn_s_setprio(1);
#pragma unroll
        for (int m = 0; m < 4; ++m)
#pragma unroll
            for (int n = 0; n < 4; ++n)
#pragma unroll
                for (int kk = 0; kk < 2; ++kk)
                    acc[m][n] = __builtin_amdgcn_mfma_f32_16x16x32_bf16(
                        aF[m][kk], bF[n][kk], acc[m][n], 0, 0, 0);
        __builtin_amdgcn_s_setprio(0);
        __syncthreads();
        if (T + 1 < NT) { const int T1 = T + 1; STG128; }
    }

    // ---- two-pass LDS-staged epilogue (waves 0-3 then 4-7 share 32KB) ----
    const int w4 = w & 3;
    const int pass = w >> 2;
    char* sw = smem + w4 * 8192;   // [64 r][64 c] bf16 swizzled ^((r&7)<<4)
    const int rl = lane >> 3, cl = lane & 7;

#pragma unroll
    for (int p = 0; p < 2; ++p) {
        __syncthreads();
        if (pass == p) {
#pragma unroll
            for (int n = 0; n < 4; ++n)
#pragma unroll
                for (int m = 0; m < 4; ++m)
#pragma unroll
                    for (int j = 0; j < 4; ++j) {
                        const int r = m * 16 + lg * 4 + j;
                        const int cb = ((n * 16 + lr) * 2) ^ ((r & 7) << 4);
                        *(unsigned short*)(sw + r * 128 + cb) = f2bfu(acc[m][n][j]);
                    }
        }
        __syncthreads();
        if (pass == p) {
#pragma unroll
            for (int it2 = 0; it2 < 8; ++it2) {
                const int r = it2 * 8 + rl;
                const int cb = (cl * 16) ^ ((r & 7) << 4);
                u16x8 val = *(const u16x8*)(sw + r * 128 + cb);
                const int gr = brow + wrow + r;
                const int gcol = bcol + wc * 64 + cl * 8;
                if (EPI == 1) {
                    *(u16x8*)(outB + (size_t)gr * ldc + gcol) = val;
                } else if (EPI == 3) {
                    unsigned short* gp = outB + (size_t)gr * ldc + gcol;
                    u16x8 gv = *(const u16x8*)gp;
                    u16x8 ov;
#pragma unroll
                    for (int e = 0; e < 8; ++e) {
                        float g = bfu2f(gv[e]);
                        float uu = bfu2f(val[e]);
                        ov[e] = f2bfu(g / (1.0f + __expf(-g)) * uu);
                    }
                    *(u16x8*)gp = ov;
                } else {
                    *(u16x8*)(outB + (size_t)blockIdx.y * 4194304 +
                              (size_t)gr * ldc + gcol) = val;
                }
            }
        }
    }
}

// ---------------- split-K reduce: out += sum of 4 bf16 partials ----------------
__global__ __launch_bounds__(256)
void reduce4_add(const unsigned short* __restrict__ part, float* __restrict__ out) {
    int i = blockIdx.x * 256 + threadIdx.x;
    float4 o = ((const float4*)out)[i];
#pragma unroll
    for (int sk = 0; sk < 4; ++sk) {
        u16x4 p = ((const u16x4*)(part + (size_t)sk * 4194304))[i];
        o.x += bfu2f(p[0]); o.y += bfu2f(p[1]); o.z += bfu2f(p[2]); o.w += bfu2f(p[3]);
    }
    ((float4*)out)[i] = o;
}

// ---- Flash attention (R14): static-max exp2 softmax, conv riders ----
#define PST 72
__global__ __launch_bounds__(256)
void attn_kernel(const unsigned short* __restrict__ QK, const unsigned short* __restrict__ VT,
                 unsigned short* __restrict__ O,
                 const float* __restrict__ c0, const float* __restrict__ c1,
                 const float* __restrict__ c2, unsigned short* __restrict__ cdst,
                 int nmat) {
    __shared__ __align__(16) unsigned short Ks[2][64 * 128];
    __shared__ __align__(16) unsigned short Vs[2][128 * 64];
    __shared__ __align__(16) unsigned short Ps[4][16 * PST];
    const int tid = threadIdx.x;

    if ((int)blockIdx.x >= 256) {
        const int nconv = gridDim.x - 256;
        conv_tail3(c0, c1, c2, cdst, (blockIdx.x - 256) * 256 + tid, nconv * 256, nmat);
        return;
    }

    const int lane = tid & 63;
    const int w = tid >> 6;
    const int lr = lane & 15, lg = lane >> 4;

    const int id = blockIdx.x;
    const int h = ((id & 7) << 1) | ((id >> 3) & 1);
    const int p = id >> 4;

    const unsigned short* Kb = QK + 2048 + h * 128;
    const unsigned short* Vb = VT + (size_t)(h * 128) * SEQLEN;

    int krow[4], kcb[4], vrow[4], vcb[4];
#pragma unroll
    for (int ch = 0; ch < 4; ++ch) {
        int d = ch * 4096 + w * 1024 + lane * 16;
        krow[ch] = d >> 8;
        kcb[ch]  = (d & 255) ^ ((krow[ch] & 7) << 4);
        vrow[ch] = d >> 7;
        vcb[ch]  = (d & 127) ^ ((vrow[ch] & 7) << 4);
    }

    const float sc2 = 0.08838834764831845f * 1.44269504089f;
    bf16x8 ones;
#pragma unroll
    for (int e = 0; e < 8; ++e) ones[e] = (__bf16)1.0f;

#pragma unroll 1
    for (int seg = 0; seg < 2; ++seg) {
        const int qb = seg ? (31 - p) : p;
        const int qw = qb * 64 + w * 16;
        const unsigned short* Qb = QK + (size_t)qw * 4096 + h * 128;

        bf16x8 qa[4];
#pragma unroll
        for (int c = 0; c < 4; ++c)
            qa[c] = *(const bf16x8*)(Qb + (size_t)lr * 4096 + c * 32 + lg * 8);

        f32x4 acc[8];
#pragma unroll
        for (int dt = 0; dt < 8; ++dt) acc[dt] = (f32x4){0.f, 0.f, 0.f, 0.f};
        f32x4 lacc = (f32x4){0.f, 0.f, 0.f, 0.f};
        const int ntile = qb + 1;

#pragma unroll
        for (int ch = 0; ch < 4; ++ch) {
            gload16(Kb + (size_t)krow[ch] * 4096 + (kcb[ch] >> 1),
                    (char*)&Ks[0][0] + ch * 4096 + w * 1024);
            gload16(Vb + (size_t)vrow[ch] * SEQLEN + (vcb[ch] >> 1),
                    (char*)&Vs[0][0] + ch * 4096 + w * 1024);
        }
        __syncthreads();

        for (int tt = 0; tt < ntile; ++tt) {
            const int cur = tt & 1;
            const int t0 = tt * 64;
            if (tt + 1 < ntile) {
                const int t1 = t0 + 64;
#pragma unroll
                for (int ch = 0; ch < 4; ++ch) {
                    gload16(Kb + (size_t)(t1 + krow[ch]) * 4096 + (kcb[ch] >> 1),
                            (char*)&Ks[cur ^ 1][0] + ch * 4096 + w * 1024);
                    gload16(Vb + (size_t)vrow[ch] * SEQLEN + t1 + (vcb[ch] >> 1),
                            (char*)&Vs[cur ^ 1][0] + ch * 4096 + w * 1024);
                }
            }
            f32x4 s[4];
#pragma unroll
            for (int th = 0; th < 4; ++th) s[th] = (f32x4){0.f, 0.f, 0.f, 0.f};
            __builtin_amdgcn_s_setprio(1);
#pragma unroll
            for (int th = 0; th < 4; ++th) {
                const int row = th * 16 + lr;
#pragma unroll
                for (int c = 0; c < 4; ++c) {
                    bf16x8 kb = *(const bf16x8*)((char*)&Ks[cur][0] + row * 256 +
                                                 ((c * 64 + lg * 16) ^ ((lr & 7) << 4)));
                    s[th] = __builtin_amdgcn_mfma_f32_16x16x32_bf16(qa[c], kb, s[th], 0, 0, 0);
                }
            }
            __builtin_amdgcn_s_setprio(0);
            if (tt == qb) {
#pragma unroll
                for (int th = 0; th < 4; ++th) {
                    int tg = t0 + th * 16 + lr;
#pragma unroll
                    for (int jj = 0; jj < 4; ++jj) {
                        int qg = qw + lg * 4 + jj;
                        float v = s[th][jj] * sc2 + (tg <= qg ? 0.f : -1e9f);
                        s[th][jj] = exp2f(v);
                    }
                }
            } else {
#pragma unroll
                for (int th = 0; th < 4; ++th)
#pragma unroll
                    for (int jj = 0; jj < 4; ++jj)
                        s[th][jj] = exp2f(s[th][jj] * sc2);
            }
#pragma unroll
            for (int th = 0; th < 4; ++th)
#pragma unroll
                for (int jj = 0; jj < 4; ++jj)
                    Ps[w][(lg * 4 + jj) * PST + th * 16 + lr] = f2bfu(s[th][jj]);
            bf16x8 pa[2];
#pragma unroll
            for (int ks = 0; ks < 2; ++ks)
                pa[ks] = *(const bf16x8*)&Ps[w][lr * PST + ks * 32 + lg * 8];
            __builtin_amdgcn_s_setprio(1);
            lacc = __builtin_amdgcn_mfma_f32_16x16x32_bf16(pa[0], ones, lacc, 0, 0, 0);
            lacc = __builtin_amdgcn_mfma_f32_16x16x32_bf16(pa[1], ones, lacc, 0, 0, 0);
#pragma unroll
            for (int dt = 0; dt < 8; ++dt) {
                const int d = dt * 16 + lr;
#pragma unroll
                for (int ks = 0; ks < 2; ++ks) {
                    bf16x8 vb = *(const bf16x8*)((char*)&Vs[cur][0] + d * 128 +
                                                 ((ks * 64 + lg * 16) ^ ((lr & 7) << 4)));
                    acc[dt] = __builtin_amdgcn_mfma_f32_16x16x32_bf16(pa[ks], vb, acc[dt], 0, 0, 0);
                }
            }
            __builtin_amdgcn_s_setprio(0);
            __syncthreads();
        }
        float invl[4];
#pragma unroll
        for (int jj = 0; jj < 4; ++jj) invl[jj] = 1.0f / lacc[jj];
#pragma unroll
        for (int dt = 0; dt < 8; ++dt)
#pragma unroll
            for (int jj = 0; jj < 4; ++jj)
                O[(size_t)(qw + lg * 4 + jj) * HIDN + h * HDIM + dt * 16 + lr] =
                    f2bfu(acc[dt][jj] * invl[jj]);
    }
}

extern "C" void kernel_launch(void* const* d_in, const int* in_sizes, int n_in,
                              void* d_out, int out_size, void* d_ws, size_t ws_size,
                              hipStream_t stream) {
    const float* hidden = (const float*)d_in[0];
    const float* ln1w = (const float*)d_in[2];
    const float* ln1b = (const float*)d_in[3];
    const float* ln2w = (const float*)d_in[4];
    const float* ln2b = (const float*)d_in[5];
    const float* wq = (const float*)d_in[6];
    const float* bq = (const float*)d_in[7];
    const float* wk = (const float*)d_in[8];
    const float* bk = (const float*)d_in[9];
    const float* wv = (const float*)d_in[10];
    const float* bv = (const float*)d_in[11];
    const float* wo = (const float*)d_in[12];
    const float* bo = (const float*)d_in[13];
    const float* wg = (const float*)d_in[14];
    const float* wu = (const float*)d_in[15];
    const float* wd = (const float*)d_in[16];
    const int* tsl = (const int*)d_in[17];
    float* out = (float*)d_out;

    char* ws = (char*)d_ws;
    const size_t MB = 1024 * 1024;
    unsigned short* Wbuf = (unsigned short*)(ws);            // 32 MiB: qkv(24) + wo(8)
    unsigned short* qk   = (unsigned short*)(ws + 32 * MB);  // 16 MiB
    unsigned short* vt   = (unsigned short*)(ws + 48 * MB);  // 8 MiB
    unsigned short* x_bf = (unsigned short*)(ws + 56 * MB);  // 8 MiB; attn out reuses
    unsigned short* g_bf = (unsigned short*)(ws + 64 * MB);  // 32 MiB; WO partials reuse
    unsigned short* part = qk;                               // 32 MiB for down partials
    unsigned short* y_bf = vt;

    const int HID2 = HIDN * HIDN;
    const int FFE  = FFDIM * HIDN;
    const int CONV_HID = HID2 / 8 / 256;
    const int CONV_FF  = FFE / 8 / 256;
    const size_t LDSZ = 131072;
    const size_t LDSZ128 = 49152;

    int nmat = 0;
    if (ws_size >= 192 * MB) nmat = 3;
    else if (ws_size >= 160 * MB) nmat = 2;
    else if (ws_size >= 128 * MB) nmat = 1;
    unsigned short* wgBuf = (nmat > 0) ? (unsigned short*)(ws + 96 * MB) : Wbuf;
    unsigned short* wuBuf = (nmat > 1) ? wgBuf + (size_t)FFE : Wbuf;
    unsigned short* wdBuf = (nmat > 2) ? wgBuf + 2 * (size_t)FFE : Wbuf;

    // ---- QKV (tail blocks convert wo) ----
    conv3_f32_bf16<<<3 * CONV_HID, 256, 0, stream>>>(wq, wk, wv, Wbuf);
    ln_bf16<<<SEQLEN, 256, 0, stream>>>(hidden, ln1w, ln1b, x_bf);
    gemm256_qkv<<<256, 512, LDSZ, stream>>>(
        x_bf, HIDN, Wbuf, HIDN, HIDN, 24, bq, bk, bv, qk, vt,
        192, wo, Wbuf + 3 * (size_t)HID2, HID2 / 8);
    rope_kernel<<<SEQLEN * 32 * 64 / 256, 256, 0, stream>>>(qk, tsl);

    // ---- attention (conv riders convert wg/wu/wd) ----
    if (nmat > 0) {
        attn_kernel<<<768, 256, 0, stream>>>(qk, vt, x_bf, wg, wu, wd, wgBuf, nmat);
    } else {
        attn_kernel<<<256, 256, 0, stream>>>(qk, vt, x_bf, nullptr, nullptr, nullptr,
                                             nullptr, 0);
    }

    // ---- WO + residual + LN2 (split-K=4, 128x256 tiles, 512 blocks) ----
    gemm128<4><<<dim3(128, 4), 512, LDSZ128, stream>>>(
        x_bf, HIDN, Wbuf + 3 * (size_t)HID2, HIDN, 512, 8, HIDN, g_bf);
    wo_ln<<<SEQLEN, 256, 0, stream>>>(g_bf, hidden, bo, ln2w, ln2b, out, y_bf);

    // ---- FFN (128x256 tiles, 512 blocks = 2/CU) ----
    if (nmat < 1) conv_f32_bf16<<<CONV_FF, 256, 0, stream>>>(wg, Wbuf);
    gemm128<1><<<dim3(512, 1), 512, LDSZ128, stream>>>(
        y_bf, HIDN, wgBuf, HIDN, HIDN, 32, FFDIM, g_bf);
    if (nmat < 2) conv_f32_bf16<<<CONV_FF, 256, 0, stream>>>(wu, Wbuf);
    gemm128<3><<<dim3(512, 1), 512, LDSZ128, stream>>>(
        y_bf, HIDN, wuBuf, HIDN, HIDN, 32, FFDIM, g_bf);
    if (nmat < 3) conv_f32_bf16<<<CONV_FF, 256, 0, stream>>>(wd, Wbuf);
    gemm128<4><<<dim3(128, 4), 512, LDSZ128, stream>>>(
        g_bf, FFDIM, wdBuf, FFDIM, 2048, 8, HIDN, part);
    reduce4_add<<<4096, 256, 0, stream>>>(part, out);
}

// Round 16
// 404.508 us; speedup vs baseline: 1.4184x; 1.4184x over previous
//
#include <hip/hip_runtime.h>

#define HIDN 2048
#define NHEAD 16
#define HDIM 128
#define FFDIM 8192
#define SEQLEN 2048

typedef __attribute__((ext_vector_type(8))) __bf16 bf16x8;
typedef __attribute__((ext_vector_type(4))) float f32x4;
typedef __attribute__((ext_vector_type(4))) unsigned short u16x4;
typedef __attribute__((ext_vector_type(8))) unsigned short u16x8;

__device__ __forceinline__ unsigned short f2bfu(float f) {
    unsigned int u = __float_as_uint(f);
    unsigned int r = u + 0x7fffu + ((u >> 16) & 1u);
    return (unsigned short)(r >> 16);
}
__device__ __forceinline__ float bfu2f(unsigned short u) {
    return __uint_as_float(((unsigned int)u) << 16);
}

__device__ __forceinline__ void gload16(const void* g, void* l) {
    __builtin_amdgcn_global_load_lds(
        (const __attribute__((address_space(1))) unsigned int*)g,
        (__attribute__((address_space(3))) unsigned int*)l,
        16, 0, 0);
}

__device__ __forceinline__ void conv_groups(const float* __restrict__ src,
                                            unsigned short* __restrict__ dst,
                                            int i0, int stride, int n8) {
    for (int i = i0; i < n8; i += stride) {
        float4 a = ((const float4*)src)[i * 2];
        float4 b = ((const float4*)src)[i * 2 + 1];
        u16x8 v;
        v[0] = f2bfu(a.x); v[1] = f2bfu(a.y); v[2] = f2bfu(a.z); v[3] = f2bfu(a.w);
        v[4] = f2bfu(b.x); v[5] = f2bfu(b.y); v[6] = f2bfu(b.z); v[7] = f2bfu(b.w);
        *(u16x8*)(dst + (size_t)i * 8) = v;
    }
}

__device__ __forceinline__ void conv_tail3(const float* __restrict__ s0,
                                           const float* __restrict__ s1,
                                           const float* __restrict__ s2,
                                           unsigned short* __restrict__ dst,
                                           int i0, int stride, int nmat) {
    const int FF8 = FFDIM * HIDN / 8;
    const int tot = nmat * FF8;
    for (int i = i0; i < tot; i += stride) {
        int m = i >> 21;
        int li = i & (FF8 - 1);
        const float* s = (m == 0) ? s0 : (m == 1) ? s1 : s2;
        float4 a = ((const float4*)s)[li * 2];
        float4 b = ((const float4*)s)[li * 2 + 1];
        u16x8 v;
        v[0] = f2bfu(a.x); v[1] = f2bfu(a.y); v[2] = f2bfu(a.z); v[3] = f2bfu(a.w);
        v[4] = f2bfu(b.x); v[5] = f2bfu(b.y); v[6] = f2bfu(b.z); v[7] = f2bfu(b.w);
        *(u16x8*)(dst + (size_t)i * 8) = v;
    }
}

// ---------------- fp32 -> bf16 weight conversion (standalone) ----------------
__global__ __launch_bounds__(256)
void conv_f32_bf16(const float* __restrict__ src, unsigned short* __restrict__ dst) {
    int i = blockIdx.x * 256 + threadIdx.x;
    conv_groups(src, dst, i, 1 << 30, i + 1);
}

// ---- fused prep: blocks 0..6143 convert wq/wk/wv; blocks 6144..8191 do LN1 ----
__global__ __launch_bounds__(256)
void prep_qkv(const float* __restrict__ s0, const float* __restrict__ s1,
              const float* __restrict__ s2, unsigned short* __restrict__ dst,
              const float* __restrict__ x, const float* __restrict__ lw,
              const float* __restrict__ lb, unsigned short* __restrict__ xout) {
    const int tid = threadIdx.x;
    if ((int)blockIdx.x < 6144) {
        int i = blockIdx.x * 256 + tid;
        int m = i >> 19;
        int li = i & ((1 << 19) - 1);
        const float* s = (m == 0) ? s0 : (m == 1) ? s1 : s2;
        float4 a = ((const float4*)s)[li * 2];
        float4 b = ((const float4*)s)[li * 2 + 1];
        u16x8 v;
        v[0] = f2bfu(a.x); v[1] = f2bfu(a.y); v[2] = f2bfu(a.z); v[3] = f2bfu(a.w);
        v[4] = f2bfu(b.x); v[5] = f2bfu(b.y); v[6] = f2bfu(b.z); v[7] = f2bfu(b.w);
        *(u16x8*)(dst + (size_t)i * 8) = v;
        return;
    }
    const int row = blockIdx.x - 6144;
    const float* xr = x + (size_t)row * HIDN;
    float4 v0 = ((const float4*)xr)[tid];
    float4 v1 = ((const float4*)xr)[tid + 256];
    float s = v0.x + v0.y + v0.z + v0.w + v1.x + v1.y + v1.z + v1.w;
    float q = v0.x*v0.x + v0.y*v0.y + v0.z*v0.z + v0.w*v0.w
            + v1.x*v1.x + v1.y*v1.y + v1.z*v1.z + v1.w*v1.w;
    for (int o = 32; o > 0; o >>= 1) {
        s += __shfl_down(s, o, 64);
        q += __shfl_down(q, o, 64);
    }
    __shared__ float red[8];
    const int wid = tid >> 6;
    if ((tid & 63) == 0) { red[wid] = s; red[4 + wid] = q; }
    __syncthreads();
    float st = red[0] + red[1] + red[2] + red[3];
    float qt = red[4] + red[5] + red[6] + red[7];
    float mu = st * (1.0f / HIDN);
    float var = qt * (1.0f / HIDN) - mu * mu;
    float rs = rsqrtf(var + 1e-5f);
    unsigned short* orow = xout + (size_t)row * HIDN;
    int i0 = tid * 4, i1 = (tid + 256) * 4;
    orow[i0 + 0] = f2bfu((v0.x - mu) * rs * lw[i0 + 0] + lb[i0 + 0]);
    orow[i0 + 1] = f2bfu((v0.y - mu) * rs * lw[i0 + 1] + lb[i0 + 1]);
    orow[i0 + 2] = f2bfu((v0.z - mu) * rs * lw[i0 + 2] + lb[i0 + 2]);
    orow[i0 + 3] = f2bfu((v0.w - mu) * rs * lw[i0 + 3] + lb[i0 + 3]);
    orow[i1 + 0] = f2bfu((v1.x - mu) * rs * lw[i1 + 0] + lb[i1 + 0]);
    orow[i1 + 1] = f2bfu((v1.y - mu) * rs * lw[i1 + 1] + lb[i1 + 1]);
    orow[i1 + 2] = f2bfu((v1.z - mu) * rs * lw[i1 + 2] + lb[i1 + 2]);
    orow[i1 + 3] = f2bfu((v1.w - mu) * rs * lw[i1 + 3] + lb[i1 + 3]);
}

// ---------------- WO combine + residual + LN2, one block per row ----------------
__global__ __launch_bounds__(256)
void wo_ln(const unsigned short* __restrict__ part, const float* __restrict__ h,
           const float* __restrict__ bo, const float* __restrict__ w,
           const float* __restrict__ b, float* __restrict__ out,
           unsigned short* __restrict__ ybf) {
    const int row = blockIdx.x;
    const int tid = threadIdx.x;
    const int c0 = tid * 4, c1 = (tid + 256) * 4;
    float4 o0 = ((const float4*)(h + (size_t)row * HIDN))[tid];
    float4 o1 = ((const float4*)(h + (size_t)row * HIDN))[tid + 256];
    o0.x += bo[c0]; o0.y += bo[c0 + 1]; o0.z += bo[c0 + 2]; o0.w += bo[c0 + 3];
    o1.x += bo[c1]; o1.y += bo[c1 + 1]; o1.z += bo[c1 + 2]; o1.w += bo[c1 + 3];
#pragma unroll
    for (int sk = 0; sk < 4; ++sk) {
        const unsigned short* pr = part + (size_t)sk * 4194304 + (size_t)row * HIDN;
        u16x4 p0 = *(const u16x4*)(pr + c0);
        u16x4 p1 = *(const u16x4*)(pr + c1);
        o0.x += bfu2f(p0[0]); o0.y += bfu2f(p0[1]); o0.z += bfu2f(p0[2]); o0.w += bfu2f(p0[3]);
        o1.x += bfu2f(p1[0]); o1.y += bfu2f(p1[1]); o1.z += bfu2f(p1[2]); o1.w += bfu2f(p1[3]);
    }
    ((float4*)(out + (size_t)row * HIDN))[tid] = o0;
    ((float4*)(out + (size_t)row * HIDN))[tid + 256] = o1;
    float s = o0.x + o0.y + o0.z + o0.w + o1.x + o1.y + o1.z + o1.w;
    float q = o0.x*o0.x + o0.y*o0.y + o0.z*o0.z + o0.w*o0.w
            + o1.x*o1.x + o1.y*o1.y + o1.z*o1.z + o1.w*o1.w;
    for (int o = 32; o > 0; o >>= 1) {
        s += __shfl_down(s, o, 64);
        q += __shfl_down(q, o, 64);
    }
    __shared__ float red[8];
    const int wid = tid >> 6;
    if ((tid & 63) == 0) { red[wid] = s; red[4 + wid] = q; }
    __syncthreads();
    float st = red[0] + red[1] + red[2] + red[3];
    float qt = red[4] + red[5] + red[6] + red[7];
    float mu = st * (1.0f / HIDN);
    float var = qt * (1.0f / HIDN) - mu * mu;
    float rs = rsqrtf(var + 1e-5f);
    unsigned short* yr = ybf + (size_t)row * HIDN;
    yr[c0 + 0] = f2bfu((o0.x - mu) * rs * w[c0 + 0] + b[c0 + 0]);
    yr[c0 + 1] = f2bfu((o0.y - mu) * rs * w[c0 + 1] + b[c0 + 1]);
    yr[c0 + 2] = f2bfu((o0.z - mu) * rs * w[c0 + 2] + b[c0 + 2]);
    yr[c0 + 3] = f2bfu((o0.w - mu) * rs * w[c0 + 3] + b[c0 + 3]);
    yr[c1 + 0] = f2bfu((o1.x - mu) * rs * w[c1 + 0] + b[c1 + 0]);
    yr[c1 + 1] = f2bfu((o1.y - mu) * rs * w[c1 + 1] + b[c1 + 1]);
    yr[c1 + 2] = f2bfu((o1.z - mu) * rs * w[c1 + 2] + b[c1 + 2]);
    yr[c1 + 3] = f2bfu((o1.w - mu) * rs * w[c1 + 3] + b[c1 + 3]);
}

// ---------------- RoPE in-place on qk buffer [S][4096] ----------------
__global__ __launch_bounds__(256)
void rope_kernel(unsigned short* __restrict__ qk, const int* __restrict__ tsl) {
    int id = blockIdx.x * 256 + threadIdx.x;
    int p  = id & 63;
    int hh = (id >> 6) & 31;
    int s  = id >> 11;
    int off = tsl[0] - SEQLEN;
    float inv = exp2f((float)p * -0.20762050593f);
    float ang = (float)(s + off) * inv;
    float c, sn;
    __sincosf(ang, &sn, &c);
    size_t base = (size_t)s * 4096 + hh * 128 + p;
    float x1 = bfu2f(qk[base]);
    float x2 = bfu2f(qk[base + 64]);
    qk[base]      = f2bfu(x1 * c - x2 * sn);
    qk[base + 64] = f2bfu(x2 * c + x1 * sn);
}

// ======= 256x256 8-phase GEMM (R8 schedule) + optional tail-conv blocks =======
#define BAR __builtin_amdgcn_s_barrier()
#define VM4 asm volatile("s_waitcnt vmcnt(4)" ::: "memory")
#define VM0 asm volatile("s_waitcnt vmcnt(0)" ::: "memory")

#define STAGE_A(tile, h) { const int k0_ = k_start + (tile) * 64;                      \
  _Pragma("unroll") for (int i_ = 0; i_ < 2; ++i_) {                                   \
    int d_ = (h) * 16384 + i_ * 8192 + tid * 16;                                       \
    int r_ = d_ >> 7;                                                                  \
    int cb_ = (d_ & 127) ^ ((r_ & 7) << 4);                                            \
    gload16((const char*)Ab + ((size_t)(brow + r_) * lda + k0_) * 2 + cb_,             \
            smem + ((tile) & 1) * 65536 + (h) * 16384 + i_ * 8192 + w * 1024); } }

#define STAGE_B(tile, h) { const int k0_ = k_start + (tile) * 64;                      \
  _Pragma("unroll") for (int i_ = 0; i_ < 2; ++i_) {                                   \
    int d_ = (h) * 16384 + i_ * 8192 + tid * 16;                                       \
    int r_ = d_ >> 7;                                                                  \
    int cb_ = (d_ & 127) ^ ((r_ & 7) << 4);                                            \
    gload16((const char*)Bb + ((size_t)(bcol + r_) * ldb + k0_) * 2 + cb_,             \
            smem + ((tile) & 1) * 65536 + 32768 + (h) * 16384 + i_ * 8192 + w * 1024); } }

#define LDB(BO)                                                                        \
  _Pragma("unroll") for (int n_ = 0; n_ < 4; ++n_)                                     \
  _Pragma("unroll") for (int kk_ = 0; kk_ < 2; ++kk_)                                  \
    bF[n_][kk_] = *(const bf16x8*)(smem + (BO) + bbase + n_ * 2048 + colb[kk_]);

#define LDA2(BO, MP)                                                                   \
  _Pragma("unroll") for (int dm_ = 0; dm_ < 2; ++dm_)                                  \
  _Pragma("unroll") for (int kk_ = 0; kk_ < 2; ++kk_)                                  \
    aF[dm_][kk_] = *(const bf16x8*)(smem + (BO) + abase + ((MP) * 2 + dm_) * 2048 + colb[kk_]);

#define MM(MP)                                                                         \
  __builtin_amdgcn_s_setprio(1);                                                       \
  _Pragma("unroll") for (int dm_ = 0; dm_ < 2; ++dm_)                                  \
  _Pragma("unroll") for (int n_ = 0; n_ < 4; ++n_)                                     \
  _Pragma("unroll") for (int kk_ = 0; kk_ < 2; ++kk_)                                  \
    acc[(MP) * 2 + dm_][n_] = __builtin_amdgcn_mfma_f32_16x16x32_bf16(                 \
        aF[dm_][kk_], bF[n_][kk_], acc[(MP) * 2 + dm_][n_], 0, 0, 0);                  \
  __builtin_amdgcn_s_setprio(0);

template<int EPI>
__global__ __launch_bounds__(512, 1)
void gemm256(const unsigned short* __restrict__ Ab, int lda,
             const unsigned short* __restrict__ Bb, int ldb,
             int k_len, int nbx, int ldc,
             const float* __restrict__ bias0, const float* __restrict__ bias1,
             const float* __restrict__ bias2,
             unsigned short* __restrict__ outB, unsigned short* __restrict__ outV,
             int ngemm, const float* __restrict__ csrc,
             unsigned short* __restrict__ cdst, int conv_n8) {
    extern __shared__ char smem[];   // 131072 bytes
    const int tid = threadIdx.x;

    if ((int)blockIdx.x >= ngemm) {
        if (blockIdx.y == 0) {
            const int nconv = gridDim.x - ngemm;
            conv_groups(csrc, cdst, (blockIdx.x - ngemm) * 512 + tid, nconv * 512, conv_n8);
        }
        return;
    }

    const int w = tid >> 6, lane = tid & 63;
    const int lr = lane & 15, lg = lane >> 4;
    const int wrow = (w >> 2) * 128;
    const int wc = w & 3;

    const int cpx = nbx >> 3;
    const int xcd = blockIdx.x & 7;
    const int loc = blockIdx.x >> 3;
    const int bx = xcd * cpx + loc % cpx;
    const int by = loc / cpx;
    const int brow = by * 256, bcol = bx * 256;
    const int k_start = blockIdx.y * k_len;

    const int xorv = (lr & 7) << 4;
    int colb[2];
    colb[0] = (lg * 16) ^ xorv;
    colb[1] = (64 + lg * 16) ^ xorv;
    const int abase = (wrow + lr) * 128;
    const int bbase = 32768 + (wc * 64 + lr) * 128;

    f32x4 acc[8][4];
#pragma unroll
    for (int m = 0; m < 8; ++m)
#pragma unroll
        for (int n = 0; n < 4; ++n) acc[m][n] = (f32x4){0.f, 0.f, 0.f, 0.f};

    bf16x8 bF[4][2], aF[2][2];

    const int NT = k_len >> 6;
    const int NIT = NT >> 1;

    STAGE_A(0, 0); STAGE_A(0, 1); STAGE_B(0, 0); STAGE_B(0, 1);
    STAGE_B(1, 0); STAGE_B(1, 1);
    VM4; BAR;

    for (int it = 0; it < NIT; ++it) {
        const int T = 2 * it;
        const bool s2 = (T + 2) < NT, s3 = (T + 3) < NT;
        LDB(0); LDA2(0, 0); STAGE_A(T + 1, 0); MM(0); BAR;
        LDA2(0, 1); STAGE_A(T + 1, 1); MM(1); BAR;
        LDA2(0, 2); if (s2) STAGE_B(T + 2, 0); MM(2); BAR;
        LDA2(0, 3); if (s2) STAGE_B(T + 2, 1); MM(3);
        if (s2) { VM4; } else { VM0; }
        BAR;
        LDB(65536); LDA2(65536, 0); if (s2) STAGE_A(T + 2, 0); MM(0); BAR;
        LDA2(65536, 1); if (s2) STAGE_A(T + 2, 1); MM(1); BAR;
        LDA2(65536, 2); if (s3) STAGE_B(T + 3, 0); MM(2); BAR;
        LDA2(65536, 3); if (s3) STAGE_B(T + 3, 1); MM(3);
        if (s3) { VM4; } else { VM0; }
        BAR;
    }

    // ======== LDS-staged epilogue ========
    char* sw = smem + w * 16384;
    const bool vblk = (EPI == 0) && (bcol >= 4096);

    if (!vblk) {
#pragma unroll
        for (int n = 0; n < 4; ++n) {
            const int col = bcol + wc * 64 + n * 16 + lr;
            float bv = 0.f;
            if (EPI == 0) bv = (col < 2048) ? bias0[col] : bias1[col - 2048];
#pragma unroll
            for (int m = 0; m < 8; ++m)
#pragma unroll
                for (int j = 0; j < 4; ++j) {
                    const int r = m * 16 + lg * 4 + j;
                    const int cb = ((n * 16 + lr) * 2) ^ ((r & 7) << 4);
                    *(unsigned short*)(sw + r * 128 + cb) = f2bfu(acc[m][n][j] + bv);
                }
        }
        const int rl = lane >> 3, cl = lane & 7;
#pragma unroll
        for (int it2 = 0; it2 < 16; ++it2) {
            const int r = it2 * 8 + rl;
            const int cb = (cl * 16) ^ ((r & 7) << 4);
            u16x8 val = *(const u16x8*)(sw + r * 128 + cb);
            const int gr = brow + wrow + r;
            const int gcol = bcol + wc * 64 + cl * 8;
            if (EPI == 0) {
                *(u16x8*)(outB + (size_t)gr * 4096 + gcol) = val;
            } else if (EPI == 1) {
                *(u16x8*)(outB + (size_t)gr * ldc + gcol) = val;
            } else if (EPI == 3) {
                unsigned short* gp = outB + (size_t)gr * ldc + gcol;
                u16x8 gv = *(const u16x8*)gp;
                u16x8 ov;
#pragma unroll
                for (int e = 0; e < 8; ++e) {
                    float g = bfu2f(gv[e]);
                    float uu = bfu2f(val[e]);
                    ov[e] = f2bfu(g / (1.0f + __expf(-g)) * uu);
                }
                *(u16x8*)gp = ov;
            } else {
                *(u16x8*)(outB + (size_t)blockIdx.y * 4194304 + (size_t)gr * ldc + gcol) = val;
            }
        }
    } else {
#pragma unroll
        for (int n = 0; n < 4; ++n) {
            const int c = n * 16 + lr;
            const float bv = bias2[bcol - 4096 + wc * 64 + c];
            const int cx = (c & 7) << 4;
#pragma unroll
            for (int m = 0; m < 8; ++m) {
                const int r0 = m * 16 + lg * 4;
                u16x4 pk;
#pragma unroll
                for (int j = 0; j < 4; ++j) pk[j] = f2bfu(acc[m][n][j] + bv);
                *(u16x4*)(sw + c * 256 + ((r0 * 2) ^ cx)) = pk;
            }
        }
        const int cg = lane >> 4, rl2 = lane & 15;
#pragma unroll
        for (int it2 = 0; it2 < 16; ++it2) {
            const int c = it2 * 4 + cg;
            const int rb = (rl2 * 16) ^ ((c & 7) << 4);
            u16x8 val = *(const u16x8*)(sw + c * 256 + rb);
            const int d = bcol - 4096 + wc * 64 + c;
            *(u16x8*)(outV + (size_t)d * SEQLEN + brow + wrow + rl2 * 8) = val;
        }
    }
}

// ---------------- split-K reduce: out += sum of 4 bf16 partials ----------------
__global__ __launch_bounds__(256)
void reduce4_add(const unsigned short* __restrict__ part, float* __restrict__ out) {
    int i = blockIdx.x * 256 + threadIdx.x;
    float4 o = ((const float4*)out)[i];
#pragma unroll
    for (int sk = 0; sk < 4; ++sk) {
        u16x4 p = ((const u16x4*)(part + (size_t)sk * 4194304))[i];
        o.x += bfu2f(p[0]); o.y += bfu2f(p[1]); o.z += bfu2f(p[2]); o.w += bfu2f(p[3]);
    }
    ((float4*)out)[i] = o;
}

// ---- Flash attention: static-max exp2 softmax, l via ones-MFMA, conv riders ----
#define PST 72
__global__ __launch_bounds__(256)
void attn_kernel(const unsigned short* __restrict__ QK, const unsigned short* __restrict__ VT,
                 unsigned short* __restrict__ O,
                 const float* __restrict__ c0, const float* __restrict__ c1,
                 const float* __restrict__ c2, unsigned short* __restrict__ cdst,
                 int nmat) {
    __shared__ __align__(16) unsigned short Ks[2][64 * 128];
    __shared__ __align__(16) unsigned short Vs[2][128 * 64];
    __shared__ __align__(16) unsigned short Ps[4][16 * PST];
    const int tid = threadIdx.x;

    if ((int)blockIdx.x >= 256) {
        const int nconv = gridDim.x - 256;
        conv_tail3(c0, c1, c2, cdst, (blockIdx.x - 256) * 256 + tid, nconv * 256, nmat);
        return;
    }

    const int lane = tid & 63;
    const int w = tid >> 6;
    const int lr = lane & 15, lg = lane >> 4;

    const int id = blockIdx.x;
    const int h = ((id & 7) << 1) | ((id >> 3) & 1);
    const int p = id >> 4;

    const unsigned short* Kb = QK + 2048 + h * 128;
    const unsigned short* Vb = VT + (size_t)(h * 128) * SEQLEN;

    int krow[4], kcb[4], vrow[4], vcb[4];
#pragma unroll
    for (int ch = 0; ch < 4; ++ch) {
        int d = ch * 4096 + w * 1024 + lane * 16;
        krow[ch] = d >> 8;
        kcb[ch]  = (d & 255) ^ ((krow[ch] & 7) << 4);
        vrow[ch] = d >> 7;
        vcb[ch]  = (d & 127) ^ ((vrow[ch] & 7) << 4);
    }

    const float sc2 = 0.08838834764831845f * 1.44269504089f;
    bf16x8 ones;
#pragma unroll
    for (int e = 0; e < 8; ++e) ones[e] = (__bf16)1.0f;

#pragma unroll 1
    for (int seg = 0; seg < 2; ++seg) {
        const int qb = seg ? (31 - p) : p;
        const int qw = qb * 64 + w * 16;
        const unsigned short* Qb = QK + (size_t)qw * 4096 + h * 128;

        bf16x8 qa[4];
#pragma unroll
        for (int c = 0; c < 4; ++c)
            qa[c] = *(const bf16x8*)(Qb + (size_t)lr * 4096 + c * 32 + lg * 8);

        f32x4 acc[8];
#pragma unroll
        for (int dt = 0; dt < 8; ++dt) acc[dt] = (f32x4){0.f, 0.f, 0.f, 0.f};
        f32x4 lacc = (f32x4){0.f, 0.f, 0.f, 0.f};
        const int ntile = qb + 1;

#pragma unroll
        for (int ch = 0; ch < 4; ++ch) {
            gload16(Kb + (size_t)krow[ch] * 4096 + (kcb[ch] >> 1),
                    (char*)&Ks[0][0] + ch * 4096 + w * 1024);
            gload16(Vb + (size_t)vrow[ch] * SEQLEN + (vcb[ch] >> 1),
                    (char*)&Vs[0][0] + ch * 4096 + w * 1024);
        }
        __syncthreads();

        for (int tt = 0; tt < ntile; ++tt) {
            const int cur = tt & 1;
            const int t0 = tt * 64;
            if (tt + 1 < ntile) {
                const int t1 = t0 + 64;
#pragma unroll
                for (int ch = 0; ch < 4; ++ch) {
                    gload16(Kb + (size_t)(t1 + krow[ch]) * 4096 + (kcb[ch] >> 1),
                            (char*)&Ks[cur ^ 1][0] + ch * 4096 + w * 1024);
                    gload16(Vb + (size_t)vrow[ch] * SEQLEN + t1 + (vcb[ch] >> 1),
                            (char*)&Vs[cur ^ 1][0] + ch * 4096 + w * 1024);
                }
            }
            f32x4 s[4];
#pragma unroll
            for (int th = 0; th < 4; ++th) s[th] = (f32x4){0.f, 0.f, 0.f, 0.f};
            __builtin_amdgcn_s_setprio(1);
#pragma unroll
            for (int th = 0; th < 4; ++th) {
                const int row = th * 16 + lr;
#pragma unroll
                for (int c = 0; c < 4; ++c) {
                    bf16x8 kb = *(const bf16x8*)((char*)&Ks[cur][0] + row * 256 +
                                                 ((c * 64 + lg * 16) ^ ((lr & 7) << 4)));
                    s[th] = __builtin_amdgcn_mfma_f32_16x16x32_bf16(qa[c], kb, s[th], 0, 0, 0);
                }
            }
            __builtin_amdgcn_s_setprio(0);
            if (tt == qb) {
#pragma unroll
                for (int th = 0; th < 4; ++th) {
                    int tg = t0 + th * 16 + lr;
#pragma unroll
                    for (int jj = 0; jj < 4; ++jj) {
                        int qg = qw + lg * 4 + jj;
                        float v = s[th][jj] * sc2 + (tg <= qg ? 0.f : -1e9f);
                        s[th][jj] = exp2f(v);
                    }
                }
            } else {
#pragma unroll
                for (int th = 0; th < 4; ++th)
#pragma unroll
                    for (int jj = 0; jj < 4; ++jj)
                        s[th][jj] = exp2f(s[th][jj] * sc2);
            }
#pragma unroll
            for (int th = 0; th < 4; ++th)
#pragma unroll
                for (int jj = 0; jj < 4; ++jj)
                    Ps[w][(lg * 4 + jj) * PST + th * 16 + lr] = f2bfu(s[th][jj]);
            bf16x8 pa[2];
#pragma unroll
            for (int ks = 0; ks < 2; ++ks)
                pa[ks] = *(const bf16x8*)&Ps[w][lr * PST + ks * 32 + lg * 8];
            __builtin_amdgcn_s_setprio(1);
            lacc = __builtin_amdgcn_mfma_f32_16x16x32_bf16(pa[0], ones, lacc, 0, 0, 0);
            lacc = __builtin_amdgcn_mfma_f32_16x16x32_bf16(pa[1], ones, lacc, 0, 0, 0);
#pragma unroll
            for (int dt = 0; dt < 8; ++dt) {
                const int d = dt * 16 + lr;
#pragma unroll
                for (int ks = 0; ks < 2; ++ks) {
                    bf16x8 vb = *(const bf16x8*)((char*)&Vs[cur][0] + d * 128 +
                                                 ((ks * 64 + lg * 16) ^ ((lr & 7) << 4)));
                    acc[dt] = __builtin_amdgcn_mfma_f32_16x16x32_bf16(pa[ks], vb, acc[dt], 0, 0, 0);
                }
            }
            __builtin_amdgcn_s_setprio(0);
            __syncthreads();
        }
        float invl[4];
#pragma unroll
        for (int jj = 0; jj < 4; ++jj) invl[jj] = 1.0f / lacc[jj];
#pragma unroll
        for (int dt = 0; dt < 8; ++dt)
#pragma unroll
            for (int jj = 0; jj < 4; ++jj)
                O[(size_t)(qw + lg * 4 + jj) * HIDN + h * HDIM + dt * 16 + lr] =
                    f2bfu(acc[dt][jj] * invl[jj]);
    }
}

extern "C" void kernel_launch(void* const* d_in, const int* in_sizes, int n_in,
                              void* d_out, int out_size, void* d_ws, size_t ws_size,
                              hipStream_t stream) {
    const float* hidden = (const float*)d_in[0];
    const float* ln1w = (const float*)d_in[2];
    const float* ln1b = (const float*)d_in[3];
    const float* ln2w = (const float*)d_in[4];
    const float* ln2b = (const float*)d_in[5];
    const float* wq = (const float*)d_in[6];
    const float* bq = (const float*)d_in[7];
    const float* wk = (const float*)d_in[8];
    const float* bk = (const float*)d_in[9];
    const float* wv = (const float*)d_in[10];
    const float* bv = (const float*)d_in[11];
    const float* wo = (const float*)d_in[12];
    const float* bo = (const float*)d_in[13];
    const float* wg = (const float*)d_in[14];
    const float* wu = (const float*)d_in[15];
    const float* wd = (const float*)d_in[16];
    const int* tsl = (const int*)d_in[17];
    float* out = (float*)d_out;

    char* ws = (char*)d_ws;
    const size_t MB = 1024 * 1024;
    unsigned short* Wbuf = (unsigned short*)(ws);            // 32 MiB: qkv(24) + wo(8)
    unsigned short* qk   = (unsigned short*)(ws + 32 * MB);  // 16 MiB
    unsigned short* vt   = (unsigned short*)(ws + 48 * MB);  // 8 MiB
    unsigned short* x_bf = (unsigned short*)(ws + 56 * MB);  // 8 MiB; attn out reuses
    unsigned short* g_bf = (unsigned short*)(ws + 64 * MB);  // 32 MiB; WO partials reuse
    unsigned short* part = qk;                               // 32 MiB for down partials
    unsigned short* y_bf = vt;

    const int HID2 = HIDN * HIDN;
    const int FFE  = FFDIM * HIDN;
    const int CONV_FF  = FFE / 8 / 256;
    const size_t LDSZ = 131072;

    int nmat = 0;
    if (ws_size >= 192 * MB) nmat = 3;
    else if (ws_size >= 160 * MB) nmat = 2;
    else if (ws_size >= 128 * MB) nmat = 1;
    unsigned short* wgBuf = (nmat > 0) ? (unsigned short*)(ws + 96 * MB) : Wbuf;
    unsigned short* wuBuf = (nmat > 1) ? wgBuf + (size_t)FFE : Wbuf;
    unsigned short* wdBuf = (nmat > 2) ? wgBuf + 2 * (size_t)FFE : Wbuf;

    // ---- fused prep: convert wq/wk/wv + LN1 in one launch ----
    prep_qkv<<<6144 + 2048, 256, 0, stream>>>(wq, wk, wv, Wbuf,
                                              hidden, ln1w, ln1b, x_bf);
    gemm256<0><<<dim3(192 + 64, 1), 512, LDSZ, stream>>>(
        x_bf, HIDN, Wbuf, HIDN, HIDN, 24, 0, bq, bk, bv, qk, vt,
        192, wo, Wbuf + 3 * (size_t)HID2, HID2 / 8);
    rope_kernel<<<SEQLEN * 32 * 64 / 256, 256, 0, stream>>>(qk, tsl);

    // ---- attention (conv riders convert wg/wu/wd on all CUs) ----
    if (nmat > 0) {
        attn_kernel<<<768, 256, 0, stream>>>(qk, vt, x_bf, wg, wu, wd, wgBuf, nmat);
    } else {
        attn_kernel<<<256, 256, 0, stream>>>(qk, vt, x_bf, nullptr, nullptr, nullptr,
                                             nullptr, 0);
    }

    // ---- WO + residual + LN2 ----
    gemm256<4><<<dim3(64, 4), 512, LDSZ, stream>>>(
        x_bf, HIDN, Wbuf + 3 * (size_t)HID2, HIDN, 512, 8, HIDN,
        nullptr, nullptr, nullptr, g_bf, nullptr, 64, nullptr, nullptr, 0);
    wo_ln<<<SEQLEN, 256, 0, stream>>>(g_bf, hidden, bo, ln2w, ln2b, out, y_bf);

    // ---- FFN ----
    if (nmat < 1) conv_f32_bf16<<<CONV_FF, 256, 0, stream>>>(wg, Wbuf);
    gemm256<1><<<dim3(256, 1), 512, LDSZ, stream>>>(
        y_bf, HIDN, wgBuf, HIDN, HIDN, 32, FFDIM,
        nullptr, nullptr, nullptr, g_bf, nullptr, 256, nullptr, nullptr, 0);
    if (nmat < 2) conv_f32_bf16<<<CONV_FF, 256, 0, stream>>>(wu, Wbuf);
    gemm256<3><<<dim3(256, 1), 512, LDSZ, stream>>>(
        y_bf, HIDN, wuBuf, HIDN, HIDN, 32, FFDIM,
        nullptr, nullptr, nullptr, g_bf, nullptr, 256, nullptr, nullptr, 0);
    if (nmat < 3) conv_f32_bf16<<<CONV_FF, 256, 0, stream>>>(wd, Wbuf);
    gemm256<4><<<dim3(64, 4), 512, LDSZ, stream>>>(
        g_bf, FFDIM, wdBuf, FFDIM, 2048, 8, HIDN,
        nullptr, nullptr, nullptr, part, nullptr, 64, nullptr, nullptr, 0);
    reduce4_add<<<4096, 256, 0, stream>>>(part, out);
}

// Round 17
// 402.125 us; speedup vs baseline: 1.4268x; 1.0059x over previous
//
#include <hip/hip_runtime.h>

#define HIDN 2048
#define NHEAD 16
#define HDIM 128
#define FFDIM 8192
#define SEQLEN 2048

typedef __attribute__((ext_vector_type(8))) __bf16 bf16x8;
typedef __attribute__((ext_vector_type(4))) float f32x4;
typedef __attribute__((ext_vector_type(4))) unsigned short u16x4;
typedef __attribute__((ext_vector_type(8))) unsigned short u16x8;

__device__ __forceinline__ unsigned short f2bfu(float f) {
    unsigned int u = __float_as_uint(f);
    unsigned int r = u + 0x7fffu + ((u >> 16) & 1u);
    return (unsigned short)(r >> 16);
}
__device__ __forceinline__ float bfu2f(unsigned short u) {
    return __uint_as_float(((unsigned int)u) << 16);
}

__device__ __forceinline__ void gload16(const void* g, void* l) {
    __builtin_amdgcn_global_load_lds(
        (const __attribute__((address_space(1))) unsigned int*)g,
        (__attribute__((address_space(3))) unsigned int*)l,
        16, 0, 0);
}

__device__ __forceinline__ void conv_one(const float* __restrict__ src,
                                         unsigned short* __restrict__ dst, int i) {
    float4 a = ((const float4*)src)[i * 2];
    float4 b = ((const float4*)src)[i * 2 + 1];
    u16x8 v;
    v[0] = f2bfu(a.x); v[1] = f2bfu(a.y); v[2] = f2bfu(a.z); v[3] = f2bfu(a.w);
    v[4] = f2bfu(b.x); v[5] = f2bfu(b.y); v[6] = f2bfu(b.z); v[7] = f2bfu(b.w);
    *(u16x8*)(dst + (size_t)i * 8) = v;
}

// dual-source rider: groups [0,n8a) from sa->da, [n8a, n8a+n8b) from sb->db
__device__ __forceinline__ void conv_two(const float* __restrict__ sa,
                                         unsigned short* __restrict__ da, int n8a,
                                         const float* __restrict__ sb,
                                         unsigned short* __restrict__ db, int n8b,
                                         int i0, int stride) {
    const int tot = n8a + n8b;
    for (int i = i0; i < tot; i += stride) {
        if (i < n8a) conv_one(sa, da, i);
        else         conv_one(sb, db, i - n8a);
    }
}

// up to 3 FF-sized matrices, contiguous dst
__device__ __forceinline__ void conv_tail3(const float* __restrict__ s0,
                                           const float* __restrict__ s1,
                                           const float* __restrict__ s2,
                                           unsigned short* __restrict__ dst,
                                           int i0, int stride, int nmat) {
    const int FF8 = FFDIM * HIDN / 8;
    const int tot = nmat * FF8;
    for (int i = i0; i < tot; i += stride) {
        int m = i >> 21;
        int li = i & (FF8 - 1);
        const float* s = (m == 0) ? s0 : (m == 1) ? s1 : s2;
        conv_one(s, dst + (size_t)m * FFDIM * HIDN / 8 * 8, li);
    }
}

// ---------------- fp32 -> bf16 weight conversion (standalone) ----------------
__global__ __launch_bounds__(256)
void conv_f32_bf16(const float* __restrict__ src, unsigned short* __restrict__ dst) {
    int i = blockIdx.x * 256 + threadIdx.x;
    conv_one(src, dst, i);
}

// ---- fused prep: blocks 0..6143 convert wq/wk/wv; blocks 6144..8191 do LN1 ----
__global__ __launch_bounds__(256)
void prep_qkv(const float* __restrict__ s0, const float* __restrict__ s1,
              const float* __restrict__ s2, unsigned short* __restrict__ dst,
              const float* __restrict__ x, const float* __restrict__ lw,
              const float* __restrict__ lb, unsigned short* __restrict__ xout) {
    const int tid = threadIdx.x;
    if ((int)blockIdx.x < 6144) {
        int i = blockIdx.x * 256 + tid;
        int m = i >> 19;
        int li = i & ((1 << 19) - 1);
        const float* s = (m == 0) ? s0 : (m == 1) ? s1 : s2;
        conv_one(s, dst + (size_t)m * ((1 << 19) * 8), li);
        return;
    }
    const int row = blockIdx.x - 6144;
    const float* xr = x + (size_t)row * HIDN;
    float4 v0 = ((const float4*)xr)[tid];
    float4 v1 = ((const float4*)xr)[tid + 256];
    float s = v0.x + v0.y + v0.z + v0.w + v1.x + v1.y + v1.z + v1.w;
    float q = v0.x*v0.x + v0.y*v0.y + v0.z*v0.z + v0.w*v0.w
            + v1.x*v1.x + v1.y*v1.y + v1.z*v1.z + v1.w*v1.w;
    for (int o = 32; o > 0; o >>= 1) {
        s += __shfl_down(s, o, 64);
        q += __shfl_down(q, o, 64);
    }
    __shared__ float red[8];
    const int wid = tid >> 6;
    if ((tid & 63) == 0) { red[wid] = s; red[4 + wid] = q; }
    __syncthreads();
    float st = red[0] + red[1] + red[2] + red[3];
    float qt = red[4] + red[5] + red[6] + red[7];
    float mu = st * (1.0f / HIDN);
    float var = qt * (1.0f / HIDN) - mu * mu;
    float rs = rsqrtf(var + 1e-5f);
    unsigned short* orow = xout + (size_t)row * HIDN;
    int i0 = tid * 4, i1 = (tid + 256) * 4;
    orow[i0 + 0] = f2bfu((v0.x - mu) * rs * lw[i0 + 0] + lb[i0 + 0]);
    orow[i0 + 1] = f2bfu((v0.y - mu) * rs * lw[i0 + 1] + lb[i0 + 1]);
    orow[i0 + 2] = f2bfu((v0.z - mu) * rs * lw[i0 + 2] + lb[i0 + 2]);
    orow[i0 + 3] = f2bfu((v0.w - mu) * rs * lw[i0 + 3] + lb[i0 + 3]);
    orow[i1 + 0] = f2bfu((v1.x - mu) * rs * lw[i1 + 0] + lb[i1 + 0]);
    orow[i1 + 1] = f2bfu((v1.y - mu) * rs * lw[i1 + 1] + lb[i1 + 1]);
    orow[i1 + 2] = f2bfu((v1.z - mu) * rs * lw[i1 + 2] + lb[i1 + 2]);
    orow[i1 + 3] = f2bfu((v1.w - mu) * rs * lw[i1 + 3] + lb[i1 + 3]);
}

// ---------------- WO combine + residual + LN2, one block per row ----------------
__global__ __launch_bounds__(256)
void wo_ln(const unsigned short* __restrict__ part, const float* __restrict__ h,
           const float* __restrict__ bo, const float* __restrict__ w,
           const float* __restrict__ b, float* __restrict__ out,
           unsigned short* __restrict__ ybf) {
    const int row = blockIdx.x;
    const int tid = threadIdx.x;
    const int c0 = tid * 4, c1 = (tid + 256) * 4;
    float4 o0 = ((const float4*)(h + (size_t)row * HIDN))[tid];
    float4 o1 = ((const float4*)(h + (size_t)row * HIDN))[tid + 256];
    o0.x += bo[c0]; o0.y += bo[c0 + 1]; o0.z += bo[c0 + 2]; o0.w += bo[c0 + 3];
    o1.x += bo[c1]; o1.y += bo[c1 + 1]; o1.z += bo[c1 + 2]; o1.w += bo[c1 + 3];
#pragma unroll
    for (int sk = 0; sk < 4; ++sk) {
        const unsigned short* pr = part + (size_t)sk * 4194304 + (size_t)row * HIDN;
        u16x4 p0 = *(const u16x4*)(pr + c0);
        u16x4 p1 = *(const u16x4*)(pr + c1);
        o0.x += bfu2f(p0[0]); o0.y += bfu2f(p0[1]); o0.z += bfu2f(p0[2]); o0.w += bfu2f(p0[3]);
        o1.x += bfu2f(p1[0]); o1.y += bfu2f(p1[1]); o1.z += bfu2f(p1[2]); o1.w += bfu2f(p1[3]);
    }
    ((float4*)(out + (size_t)row * HIDN))[tid] = o0;
    ((float4*)(out + (size_t)row * HIDN))[tid + 256] = o1;
    float s = o0.x + o0.y + o0.z + o0.w + o1.x + o1.y + o1.z + o1.w;
    float q = o0.x*o0.x + o0.y*o0.y + o0.z*o0.z + o0.w*o0.w
            + o1.x*o1.x + o1.y*o1.y + o1.z*o1.z + o1.w*o1.w;
    for (int o = 32; o > 0; o >>= 1) {
        s += __shfl_down(s, o, 64);
        q += __shfl_down(q, o, 64);
    }
    __shared__ float red[8];
    const int wid = tid >> 6;
    if ((tid & 63) == 0) { red[wid] = s; red[4 + wid] = q; }
    __syncthreads();
    float st = red[0] + red[1] + red[2] + red[3];
    float qt = red[4] + red[5] + red[6] + red[7];
    float mu = st * (1.0f / HIDN);
    float var = qt * (1.0f / HIDN) - mu * mu;
    float rs = rsqrtf(var + 1e-5f);
    unsigned short* yr = ybf + (size_t)row * HIDN;
    yr[c0 + 0] = f2bfu((o0.x - mu) * rs * w[c0 + 0] + b[c0 + 0]);
    yr[c0 + 1] = f2bfu((o0.y - mu) * rs * w[c0 + 1] + b[c0 + 1]);
    yr[c0 + 2] = f2bfu((o0.z - mu) * rs * w[c0 + 2] + b[c0 + 2]);
    yr[c0 + 3] = f2bfu((o0.w - mu) * rs * w[c0 + 3] + b[c0 + 3]);
    yr[c1 + 0] = f2bfu((o1.x - mu) * rs * w[c1 + 0] + b[c1 + 0]);
    yr[c1 + 1] = f2bfu((o1.y - mu) * rs * w[c1 + 1] + b[c1 + 1]);
    yr[c1 + 2] = f2bfu((o1.z - mu) * rs * w[c1 + 2] + b[c1 + 2]);
    yr[c1 + 3] = f2bfu((o1.w - mu) * rs * w[c1 + 3] + b[c1 + 3]);
}

// ---------------- RoPE in-place on qk buffer [S][4096] ----------------
__global__ __launch_bounds__(256)
void rope_kernel(unsigned short* __restrict__ qk, const int* __restrict__ tsl) {
    int id = blockIdx.x * 256 + threadIdx.x;
    int p  = id & 63;
    int hh = (id >> 6) & 31;
    int s  = id >> 11;
    int off = tsl[0] - SEQLEN;
    float inv = exp2f((float)p * -0.20762050593f);
    float ang = (float)(s + off) * inv;
    float c, sn;
    __sincosf(ang, &sn, &c);
    size_t base = (size_t)s * 4096 + hh * 128 + p;
    float x1 = bfu2f(qk[base]);
    float x2 = bfu2f(qk[base + 64]);
    qk[base]      = f2bfu(x1 * c - x2 * sn);
    qk[base + 64] = f2bfu(x2 * c + x1 * sn);
}

// ======= 256x256 8-phase GEMM (R8 schedule) + dual-source tail-conv blocks =======
#define BAR __builtin_amdgcn_s_barrier()
#define VM4 asm volatile("s_waitcnt vmcnt(4)" ::: "memory")
#define VM0 asm volatile("s_waitcnt vmcnt(0)" ::: "memory")

#define STAGE_A(tile, h) { const int k0_ = k_start + (tile) * 64;                      \
  _Pragma("unroll") for (int i_ = 0; i_ < 2; ++i_) {                                   \
    int d_ = (h) * 16384 + i_ * 8192 + tid * 16;                                       \
    int r_ = d_ >> 7;                                                                  \
    int cb_ = (d_ & 127) ^ ((r_ & 7) << 4);                                            \
    gload16((const char*)Ab + ((size_t)(brow + r_) * lda + k0_) * 2 + cb_,             \
            smem + ((tile) & 1) * 65536 + (h) * 16384 + i_ * 8192 + w * 1024); } }

#define STAGE_B(tile, h) { const int k0_ = k_start + (tile) * 64;                      \
  _Pragma("unroll") for (int i_ = 0; i_ < 2; ++i_) {                                   \
    int d_ = (h) * 16384 + i_ * 8192 + tid * 16;                                       \
    int r_ = d_ >> 7;                                                                  \
    int cb_ = (d_ & 127) ^ ((r_ & 7) << 4);                                            \
    gload16((const char*)Bb + ((size_t)(bcol + r_) * ldb + k0_) * 2 + cb_,             \
            smem + ((tile) & 1) * 65536 + 32768 + (h) * 16384 + i_ * 8192 + w * 1024); } }

#define LDB(BO)                                                                        \
  _Pragma("unroll") for (int n_ = 0; n_ < 4; ++n_)                                     \
  _Pragma("unroll") for (int kk_ = 0; kk_ < 2; ++kk_)                                  \
    bF[n_][kk_] = *(const bf16x8*)(smem + (BO) + bbase + n_ * 2048 + colb[kk_]);

#define LDA2(BO, MP)                                                                   \
  _Pragma("unroll") for (int dm_ = 0; dm_ < 2; ++dm_)                                  \
  _Pragma("unroll") for (int kk_ = 0; kk_ < 2; ++kk_)                                  \
    aF[dm_][kk_] = *(const bf16x8*)(smem + (BO) + abase + ((MP) * 2 + dm_) * 2048 + colb[kk_]);

#define MM(MP)                                                                         \
  __builtin_amdgcn_s_setprio(1);                                                       \
  _Pragma("unroll") for (int dm_ = 0; dm_ < 2; ++dm_)                                  \
  _Pragma("unroll") for (int n_ = 0; n_ < 4; ++n_)                                     \
  _Pragma("unroll") for (int kk_ = 0; kk_ < 2; ++kk_)                                  \
    acc[(MP) * 2 + dm_][n_] = __builtin_amdgcn_mfma_f32_16x16x32_bf16(                 \
        aF[dm_][kk_], bF[n_][kk_], acc[(MP) * 2 + dm_][n_], 0, 0, 0);                  \
  __builtin_amdgcn_s_setprio(0);

template<int EPI>
__global__ __launch_bounds__(512, 1)
void gemm256(const unsigned short* __restrict__ Ab, int lda,
             const unsigned short* __restrict__ Bb, int ldb,
             int k_len, int nbx, int ldc,
             const float* __restrict__ bias0, const float* __restrict__ bias1,
             const float* __restrict__ bias2,
             unsigned short* __restrict__ outB, unsigned short* __restrict__ outV,
             int ngemm,
             const float* __restrict__ csA, unsigned short* __restrict__ cdA, int n8A,
             const float* __restrict__ csB, unsigned short* __restrict__ cdB, int n8B) {
    extern __shared__ char smem[];   // 131072 bytes
    const int tid = threadIdx.x;

    if ((int)blockIdx.x >= ngemm) {
        if (blockIdx.y == 0) {
            const int nconv = gridDim.x - ngemm;
            conv_two(csA, cdA, n8A, csB, cdB, n8B,
                     (blockIdx.x - ngemm) * 512 + tid, nconv * 512);
        }
        return;
    }

    const int w = tid >> 6, lane = tid & 63;
    const int lr = lane & 15, lg = lane >> 4;
    const int wrow = (w >> 2) * 128;
    const int wc = w & 3;

    const int cpx = nbx >> 3;
    const int xcd = blockIdx.x & 7;
    const int loc = blockIdx.x >> 3;
    const int bx = xcd * cpx + loc % cpx;
    const int by = loc / cpx;
    const int brow = by * 256, bcol = bx * 256;
    const int k_start = blockIdx.y * k_len;

    const int xorv = (lr & 7) << 4;
    int colb[2];
    colb[0] = (lg * 16) ^ xorv;
    colb[1] = (64 + lg * 16) ^ xorv;
    const int abase = (wrow + lr) * 128;
    const int bbase = 32768 + (wc * 64 + lr) * 128;

    f32x4 acc[8][4];
#pragma unroll
    for (int m = 0; m < 8; ++m)
#pragma unroll
        for (int n = 0; n < 4; ++n) acc[m][n] = (f32x4){0.f, 0.f, 0.f, 0.f};

    bf16x8 bF[4][2], aF[2][2];

    const int NT = k_len >> 6;
    const int NIT = NT >> 1;

    STAGE_A(0, 0); STAGE_A(0, 1); STAGE_B(0, 0); STAGE_B(0, 1);
    STAGE_B(1, 0); STAGE_B(1, 1);
    VM4; BAR;

    for (int it = 0; it < NIT; ++it) {
        const int T = 2 * it;
        const bool s2 = (T + 2) < NT, s3 = (T + 3) < NT;
        LDB(0); LDA2(0, 0); STAGE_A(T + 1, 0); MM(0); BAR;
        LDA2(0, 1); STAGE_A(T + 1, 1); MM(1); BAR;
        LDA2(0, 2); if (s2) STAGE_B(T + 2, 0); MM(2); BAR;
        LDA2(0, 3); if (s2) STAGE_B(T + 2, 1); MM(3);
        if (s2) { VM4; } else { VM0; }
        BAR;
        LDB(65536); LDA2(65536, 0); if (s2) STAGE_A(T + 2, 0); MM(0); BAR;
        LDA2(65536, 1); if (s2) STAGE_A(T + 2, 1); MM(1); BAR;
        LDA2(65536, 2); if (s3) STAGE_B(T + 3, 0); MM(2); BAR;
        LDA2(65536, 3); if (s3) STAGE_B(T + 3, 1); MM(3);
        if (s3) { VM4; } else { VM0; }
        BAR;
    }

    // ======== LDS-staged epilogue ========
    char* sw = smem + w * 16384;
    const bool vblk = (EPI == 0) && (bcol >= 4096);

    if (!vblk) {
#pragma unroll
        for (int n = 0; n < 4; ++n) {
            const int col = bcol + wc * 64 + n * 16 + lr;
            float bv = 0.f;
            if (EPI == 0) bv = (col < 2048) ? bias0[col] : bias1[col - 2048];
#pragma unroll
            for (int m = 0; m < 8; ++m)
#pragma unroll
                for (int j = 0; j < 4; ++j) {
                    const int r = m * 16 + lg * 4 + j;
                    const int cb = ((n * 16 + lr) * 2) ^ ((r & 7) << 4);
                    *(unsigned short*)(sw + r * 128 + cb) = f2bfu(acc[m][n][j] + bv);
                }
        }
        const int rl = lane >> 3, cl = lane & 7;
#pragma unroll
        for (int it2 = 0; it2 < 16; ++it2) {
            const int r = it2 * 8 + rl;
            const int cb = (cl * 16) ^ ((r & 7) << 4);
            u16x8 val = *(const u16x8*)(sw + r * 128 + cb);
            const int gr = brow + wrow + r;
            const int gcol = bcol + wc * 64 + cl * 8;
            if (EPI == 0) {
                *(u16x8*)(outB + (size_t)gr * 4096 + gcol) = val;
            } else if (EPI == 1) {
                *(u16x8*)(outB + (size_t)gr * ldc + gcol) = val;
            } else if (EPI == 3) {
                unsigned short* gp = outB + (size_t)gr * ldc + gcol;
                u16x8 gv = *(const u16x8*)gp;
                u16x8 ov;
#pragma unroll
                for (int e = 0; e < 8; ++e) {
                    float g = bfu2f(gv[e]);
                    float uu = bfu2f(val[e]);
                    ov[e] = f2bfu(g / (1.0f + __expf(-g)) * uu);
                }
                *(u16x8*)gp = ov;
            } else {
                *(u16x8*)(outB + (size_t)blockIdx.y * 4194304 + (size_t)gr * ldc + gcol) = val;
            }
        }
    } else {
#pragma unroll
        for (int n = 0; n < 4; ++n) {
            const int c = n * 16 + lr;
            const float bv = bias2[bcol - 4096 + wc * 64 + c];
            const int cx = (c & 7) << 4;
#pragma unroll
            for (int m = 0; m < 8; ++m) {
                const int r0 = m * 16 + lg * 4;
                u16x4 pk;
#pragma unroll
                for (int j = 0; j < 4; ++j) pk[j] = f2bfu(acc[m][n][j] + bv);
                *(u16x4*)(sw + c * 256 + ((r0 * 2) ^ cx)) = pk;
            }
        }
        const int cg = lane >> 4, rl2 = lane & 15;
#pragma unroll
        for (int it2 = 0; it2 < 16; ++it2) {
            const int c = it2 * 4 + cg;
            const int rb = (rl2 * 16) ^ ((c & 7) << 4);
            u16x8 val = *(const u16x8*)(sw + c * 256 + rb);
            const int d = bcol - 4096 + wc * 64 + c;
            *(u16x8*)(outV + (size_t)d * SEQLEN + brow + wrow + rl2 * 8) = val;
        }
    }
}

// ---------------- split-K reduce: out += sum of 4 bf16 partials ----------------
__global__ __launch_bounds__(256)
void reduce4_add(const unsigned short* __restrict__ part, float* __restrict__ out) {
    int i = blockIdx.x * 256 + threadIdx.x;
    float4 o = ((const float4*)out)[i];
#pragma unroll
    for (int sk = 0; sk < 4; ++sk) {
        u16x4 p = ((const u16x4*)(part + (size_t)sk * 4194304))[i];
        o.x += bfu2f(p[0]); o.y += bfu2f(p[1]); o.z += bfu2f(p[2]); o.w += bfu2f(p[3]);
    }
    ((float4*)out)[i] = o;
}

// ---- Flash attention: static-max exp2 softmax, l via ones-MFMA, conv riders ----
#define PST 72
__global__ __launch_bounds__(256)
void attn_kernel(const unsigned short* __restrict__ QK, const unsigned short* __restrict__ VT,
                 unsigned short* __restrict__ O,
                 const float* __restrict__ c0, const float* __restrict__ c1,
                 const float* __restrict__ c2, unsigned short* __restrict__ cdst,
                 int nmat) {
    __shared__ __align__(16) unsigned short Ks[2][64 * 128];
    __shared__ __align__(16) unsigned short Vs[2][128 * 64];
    __shared__ __align__(16) unsigned short Ps[4][16 * PST];
    const int tid = threadIdx.x;

    if ((int)blockIdx.x >= 256) {
        const int nconv = gridDim.x - 256;
        conv_tail3(c0, c1, c2, cdst, (blockIdx.x - 256) * 256 + tid, nconv * 256, nmat);
        return;
    }

    const int lane = tid & 63;
    const int w = tid >> 6;
    const int lr = lane & 15, lg = lane >> 4;

    const int id = blockIdx.x;
    const int h = ((id & 7) << 1) | ((id >> 3) & 1);
    const int p = id >> 4;

    const unsigned short* Kb = QK + 2048 + h * 128;
    const unsigned short* Vb = VT + (size_t)(h * 128) * SEQLEN;

    int krow[4], kcb[4], vrow[4], vcb[4];
#pragma unroll
    for (int ch = 0; ch < 4; ++ch) {
        int d = ch * 4096 + w * 1024 + lane * 16;
        krow[ch] = d >> 8;
        kcb[ch]  = (d & 255) ^ ((krow[ch] & 7) << 4);
        vrow[ch] = d >> 7;
        vcb[ch]  = (d & 127) ^ ((vrow[ch] & 7) << 4);
    }

    const float sc2 = 0.08838834764831845f * 1.44269504089f;
    bf16x8 ones;
#pragma unroll
    for (int e = 0; e < 8; ++e) ones[e] = (__bf16)1.0f;

#pragma unroll 1
    for (int seg = 0; seg < 2; ++seg) {
        const int qb = seg ? (31 - p) : p;
        const int qw = qb * 64 + w * 16;
        const unsigned short* Qb = QK + (size_t)qw * 4096 + h * 128;

        bf16x8 qa[4];
#pragma unroll
        for (int c = 0; c < 4; ++c)
            qa[c] = *(const bf16x8*)(Qb + (size_t)lr * 4096 + c * 32 + lg * 8);

        f32x4 acc[8];
#pragma unroll
        for (int dt = 0; dt < 8; ++dt) acc[dt] = (f32x4){0.f, 0.f, 0.f, 0.f};
        f32x4 lacc = (f32x4){0.f, 0.f, 0.f, 0.f};
        const int ntile = qb + 1;

#pragma unroll
        for (int ch = 0; ch < 4; ++ch) {
            gload16(Kb + (size_t)krow[ch] * 4096 + (kcb[ch] >> 1),
                    (char*)&Ks[0][0] + ch * 4096 + w * 1024);
            gload16(Vb + (size_t)vrow[ch] * SEQLEN + (vcb[ch] >> 1),
                    (char*)&Vs[0][0] + ch * 4096 + w * 1024);
        }
        __syncthreads();

        for (int tt = 0; tt < ntile; ++tt) {
            const int cur = tt & 1;
            const int t0 = tt * 64;
            if (tt + 1 < ntile) {
                const int t1 = t0 + 64;
#pragma unroll
                for (int ch = 0; ch < 4; ++ch) {
                    gload16(Kb + (size_t)(t1 + krow[ch]) * 4096 + (kcb[ch] >> 1),
                            (char*)&Ks[cur ^ 1][0] + ch * 4096 + w * 1024);
                    gload16(Vb + (size_t)vrow[ch] * SEQLEN + t1 + (vcb[ch] >> 1),
                            (char*)&Vs[cur ^ 1][0] + ch * 4096 + w * 1024);
                }
            }
            f32x4 s[4];
#pragma unroll
            for (int th = 0; th < 4; ++th) s[th] = (f32x4){0.f, 0.f, 0.f, 0.f};
            __builtin_amdgcn_s_setprio(1);
#pragma unroll
            for (int th = 0; th < 4; ++th) {
                const int row = th * 16 + lr;
#pragma unroll
                for (int c = 0; c < 4; ++c) {
                    bf16x8 kb = *(const bf16x8*)((char*)&Ks[cur][0] + row * 256 +
                                                 ((c * 64 + lg * 16) ^ ((lr & 7) << 4)));
                    s[th] = __builtin_amdgcn_mfma_f32_16x16x32_bf16(qa[c], kb, s[th], 0, 0, 0);
                }
            }
            __builtin_amdgcn_s_setprio(0);
            if (tt == qb) {
#pragma unroll
                for (int th = 0; th < 4; ++th) {
                    int tg = t0 + th * 16 + lr;
#pragma unroll
                    for (int jj = 0; jj < 4; ++jj) {
                        int qg = qw + lg * 4 + jj;
                        float v = s[th][jj] * sc2 + (tg <= qg ? 0.f : -1e9f);
                        s[th][jj] = exp2f(v);
                    }
                }
            } else {
#pragma unroll
                for (int th = 0; th < 4; ++th)
#pragma unroll
                    for (int jj = 0; jj < 4; ++jj)
                        s[th][jj] = exp2f(s[th][jj] * sc2);
            }
#pragma unroll
            for (int th = 0; th < 4; ++th)
#pragma unroll
                for (int jj = 0; jj < 4; ++jj)
                    Ps[w][(lg * 4 + jj) * PST + th * 16 + lr] = f2bfu(s[th][jj]);
            bf16x8 pa[2];
#pragma unroll
            for (int ks = 0; ks < 2; ++ks)
                pa[ks] = *(const bf16x8*)&Ps[w][lr * PST + ks * 32 + lg * 8];
            __builtin_amdgcn_s_setprio(1);
            lacc = __builtin_amdgcn_mfma_f32_16x16x32_bf16(pa[0], ones, lacc, 0, 0, 0);
            lacc = __builtin_amdgcn_mfma_f32_16x16x32_bf16(pa[1], ones, lacc, 0, 0, 0);
#pragma unroll
            for (int dt = 0; dt < 8; ++dt) {
                const int d = dt * 16 + lr;
#pragma unroll
                for (int ks = 0; ks < 2; ++ks) {
                    bf16x8 vb = *(const bf16x8*)((char*)&Vs[cur][0] + d * 128 +
                                                 ((ks * 64 + lg * 16) ^ ((lr & 7) << 4)));
                    acc[dt] = __builtin_amdgcn_mfma_f32_16x16x32_bf16(pa[ks], vb, acc[dt], 0, 0, 0);
                }
            }
            __builtin_amdgcn_s_setprio(0);
            __syncthreads();
        }
        float invl[4];
#pragma unroll
        for (int jj = 0; jj < 4; ++jj) invl[jj] = 1.0f / lacc[jj];
#pragma unroll
        for (int dt = 0; dt < 8; ++dt)
#pragma unroll
            for (int jj = 0; jj < 4; ++jj)
                O[(size_t)(qw + lg * 4 + jj) * HIDN + h * HDIM + dt * 16 + lr] =
                    f2bfu(acc[dt][jj] * invl[jj]);
    }
}

extern "C" void kernel_launch(void* const* d_in, const int* in_sizes, int n_in,
                              void* d_out, int out_size, void* d_ws, size_t ws_size,
                              hipStream_t stream) {
    const float* hidden = (const float*)d_in[0];
    const float* ln1w = (const float*)d_in[2];
    const float* ln1b = (const float*)d_in[3];
    const float* ln2w = (const float*)d_in[4];
    const float* ln2b = (const float*)d_in[5];
    const float* wq = (const float*)d_in[6];
    const float* bq = (const float*)d_in[7];
    const float* wk = (const float*)d_in[8];
    const float* bk = (const float*)d_in[9];
    const float* wv = (const float*)d_in[10];
    const float* bv = (const float*)d_in[11];
    const float* wo = (const float*)d_in[12];
    const float* bo = (const float*)d_in[13];
    const float* wg = (const float*)d_in[14];
    const float* wu = (const float*)d_in[15];
    const float* wd = (const float*)d_in[16];
    const int* tsl = (const int*)d_in[17];
    float* out = (float*)d_out;

    char* ws = (char*)d_ws;
    const size_t MB = 1024 * 1024;
    unsigned short* Wbuf = (unsigned short*)(ws);            // 32 MiB: qkv(24) + wo(8)
    unsigned short* qk   = (unsigned short*)(ws + 32 * MB);  // 16 MiB
    unsigned short* vt   = (unsigned short*)(ws + 48 * MB);  // 8 MiB
    unsigned short* x_bf = (unsigned short*)(ws + 56 * MB);  // 8 MiB; attn out reuses
    unsigned short* g_bf = (unsigned short*)(ws + 64 * MB);  // 32 MiB; WO partials reuse
    unsigned short* part = qk;                               // 32 MiB for down partials
    unsigned short* y_bf = vt;

    const int HID2 = HIDN * HIDN;
    const int FFE  = FFDIM * HIDN;
    const int CONV_FF  = FFE / 8 / 256;
    const size_t LDSZ = 131072;

    int nmat = 0;
    if (ws_size >= 192 * MB) nmat = 3;
    else if (ws_size >= 160 * MB) nmat = 2;
    else if (ws_size >= 128 * MB) nmat = 1;
    unsigned short* wgBuf = (nmat > 0) ? (unsigned short*)(ws + 96 * MB) : Wbuf;
    unsigned short* wuBuf = (nmat > 1) ? wgBuf + (size_t)FFE : Wbuf;
    unsigned short* wdBuf = (nmat > 2) ? wgBuf + 2 * (size_t)FFE : Wbuf;

    // ---- fused prep: convert wq/wk/wv + LN1 in one launch ----
    prep_qkv<<<6144 + 2048, 256, 0, stream>>>(wq, wk, wv, Wbuf,
                                              hidden, ln1w, ln1b, x_bf);

    // ---- QKV GEMM; riders convert wo AND (if wgBuf exists) wg ----
    gemm256<0><<<dim3(192 + 64, 1), 512, LDSZ, stream>>>(
        x_bf, HIDN, Wbuf, HIDN, HIDN, 24, 0, bq, bk, bv, qk, vt,
        192,
        wo, Wbuf + 3 * (size_t)HID2, HID2 / 8,
        wg, wgBuf, (nmat >= 1) ? FFE / 8 : 0);
    rope_kernel<<<SEQLEN * 32 * 64 / 256, 256, 0, stream>>>(qk, tsl);

    // ---- attention; riders convert wu (and wd) ----
    if (nmat >= 3) {
        attn_kernel<<<768, 256, 0, stream>>>(qk, vt, x_bf, wu, wd, wd, wuBuf, 2);
    } else if (nmat == 2) {
        attn_kernel<<<768, 256, 0, stream>>>(qk, vt, x_bf, wu, wu, wu, wuBuf, 1);
    } else {
        attn_kernel<<<256, 256, 0, stream>>>(qk, vt, x_bf, nullptr, nullptr, nullptr,
                                             nullptr, 0);
    }

    // ---- WO + residual + LN2 ----
    gemm256<4><<<dim3(64, 4), 512, LDSZ, stream>>>(
        x_bf, HIDN, Wbuf + 3 * (size_t)HID2, HIDN, 512, 8, HIDN,
        nullptr, nullptr, nullptr, g_bf, nullptr, 64,
        nullptr, nullptr, 0, nullptr, nullptr, 0);
    wo_ln<<<SEQLEN, 256, 0, stream>>>(g_bf, hidden, bo, ln2w, ln2b, out, y_bf);

    // ---- FFN ----
    if (nmat < 1) conv_f32_bf16<<<CONV_FF, 256, 0, stream>>>(wg, Wbuf);
    gemm256<1><<<dim3(256, 1), 512, LDSZ, stream>>>(
        y_bf, HIDN, wgBuf, HIDN, HIDN, 32, FFDIM,
        nullptr, nullptr, nullptr, g_bf, nullptr, 256,
        nullptr, nullptr, 0, nullptr, nullptr, 0);
    if (nmat < 2) conv_f32_bf16<<<CONV_FF, 256, 0, stream>>>(wu, Wbuf);
    gemm256<3><<<dim3(256, 1), 512, LDSZ, stream>>>(
        y_bf, HIDN, wuBuf, HIDN, HIDN, 32, FFDIM,
        nullptr, nullptr, nullptr, g_bf, nullptr, 256,
        nullptr, nullptr, 0, nullptr, nullptr, 0);
    if (nmat < 3) conv_f32_bf16<<<CONV_FF, 256, 0, stream>>>(wd, Wbuf);
    gemm256<4><<<dim3(64, 4), 512, LDSZ, stream>>>(
        g_bf, FFDIM, wdBuf, FFDIM, 2048, 8, HIDN,
        nullptr, nullptr, nullptr, part, nullptr, 64,
        nullptr, nullptr, 0, nullptr, nullptr, 0);
    reduce4_add<<<4096, 256, 0, stream>>>(part, out);
}

// Round 18
// 391.769 us; speedup vs baseline: 1.4645x; 1.0264x over previous
//
#include <hip/hip_runtime.h>

#define HIDN 2048
#define NHEAD 16
#define HDIM 128
#define FFDIM 8192
#define SEQLEN 2048

typedef __attribute__((ext_vector_type(8))) __bf16 bf16x8;
typedef __attribute__((ext_vector_type(4))) float f32x4;
typedef __attribute__((ext_vector_type(4))) unsigned short u16x4;
typedef __attribute__((ext_vector_type(8))) unsigned short u16x8;

__device__ __forceinline__ unsigned short f2bfu(float f) {
    unsigned int u = __float_as_uint(f);
    unsigned int r = u + 0x7fffu + ((u >> 16) & 1u);
    return (unsigned short)(r >> 16);
}
__device__ __forceinline__ float bfu2f(unsigned short u) {
    return __uint_as_float(((unsigned int)u) << 16);
}

__device__ __forceinline__ void gload16(const void* g, void* l) {
    __builtin_amdgcn_global_load_lds(
        (const __attribute__((address_space(1))) unsigned int*)g,
        (__attribute__((address_space(3))) unsigned int*)l,
        16, 0, 0);
}

__device__ __forceinline__ void conv_one(const float* __restrict__ src,
                                         unsigned short* __restrict__ dst, int i) {
    float4 a = ((const float4*)src)[i * 2];
    float4 b = ((const float4*)src)[i * 2 + 1];
    u16x8 v;
    v[0] = f2bfu(a.x); v[1] = f2bfu(a.y); v[2] = f2bfu(a.z); v[3] = f2bfu(a.w);
    v[4] = f2bfu(b.x); v[5] = f2bfu(b.y); v[6] = f2bfu(b.z); v[7] = f2bfu(b.w);
    *(u16x8*)(dst + (size_t)i * 8) = v;
}

// dual-source rider: groups [0,n8a) from sa->da, [n8a, n8a+n8b) from sb->db
__device__ __forceinline__ void conv_two(const float* __restrict__ sa,
                                         unsigned short* __restrict__ da, int n8a,
                                         const float* __restrict__ sb,
                                         unsigned short* __restrict__ db, int n8b,
                                         int i0, int stride) {
    const int tot = n8a + n8b;
    for (int i = i0; i < tot; i += stride) {
        if (i < n8a) conv_one(sa, da, i);
        else         conv_one(sb, db, i - n8a);
    }
}

// FF-sized matrices (wg,wu,wd) into contiguous dst, over group range [start, end)
__device__ __forceinline__ void conv_tail_rng(const float* __restrict__ s0,
                                              const float* __restrict__ s1,
                                              const float* __restrict__ s2,
                                              unsigned short* __restrict__ dst,
                                              int i0, int stride, int start, int end) {
    const int FF8 = FFDIM * HIDN / 8;    // 1<<21
    for (int i = start + i0; i < end; i += stride) {
        int m = i >> 21;
        int li = i & (FF8 - 1);
        const float* s = (m == 0) ? s0 : (m == 1) ? s1 : s2;
        conv_one(s, dst + (size_t)m * FF8 * 8, li);
    }
}

// ---------------- fp32 -> bf16 weight conversion (standalone) ----------------
__global__ __launch_bounds__(256)
void conv_f32_bf16(const float* __restrict__ src, unsigned short* __restrict__ dst) {
    int i = blockIdx.x * 256 + threadIdx.x;
    conv_one(src, dst, i);
}

// ---- fused prep: blocks 0..6143 convert wq/wk/wv; blocks 6144..8191 do LN1 ----
__global__ __launch_bounds__(256)
void prep_qkv(const float* __restrict__ s0, const float* __restrict__ s1,
              const float* __restrict__ s2, unsigned short* __restrict__ dst,
              const float* __restrict__ x, const float* __restrict__ lw,
              const float* __restrict__ lb, unsigned short* __restrict__ xout) {
    const int tid = threadIdx.x;
    if ((int)blockIdx.x < 6144) {
        int i = blockIdx.x * 256 + tid;
        int m = i >> 19;
        int li = i & ((1 << 19) - 1);
        const float* s = (m == 0) ? s0 : (m == 1) ? s1 : s2;
        conv_one(s, dst + (size_t)m * ((1 << 19) * 8), li);
        return;
    }
    const int row = blockIdx.x - 6144;
    const float* xr = x + (size_t)row * HIDN;
    float4 v0 = ((const float4*)xr)[tid];
    float4 v1 = ((const float4*)xr)[tid + 256];
    float s = v0.x + v0.y + v0.z + v0.w + v1.x + v1.y + v1.z + v1.w;
    float q = v0.x*v0.x + v0.y*v0.y + v0.z*v0.z + v0.w*v0.w
            + v1.x*v1.x + v1.y*v1.y + v1.z*v1.z + v1.w*v1.w;
    for (int o = 32; o > 0; o >>= 1) {
        s += __shfl_down(s, o, 64);
        q += __shfl_down(q, o, 64);
    }
    __shared__ float red[8];
    const int wid = tid >> 6;
    if ((tid & 63) == 0) { red[wid] = s; red[4 + wid] = q; }
    __syncthreads();
    float st = red[0] + red[1] + red[2] + red[3];
    float qt = red[4] + red[5] + red[6] + red[7];
    float mu = st * (1.0f / HIDN);
    float var = qt * (1.0f / HIDN) - mu * mu;
    float rs = rsqrtf(var + 1e-5f);
    unsigned short* orow = xout + (size_t)row * HIDN;
    int i0 = tid * 4, i1 = (tid + 256) * 4;
    orow[i0 + 0] = f2bfu((v0.x - mu) * rs * lw[i0 + 0] + lb[i0 + 0]);
    orow[i0 + 1] = f2bfu((v0.y - mu) * rs * lw[i0 + 1] + lb[i0 + 1]);
    orow[i0 + 2] = f2bfu((v0.z - mu) * rs * lw[i0 + 2] + lb[i0 + 2]);
    orow[i0 + 3] = f2bfu((v0.w - mu) * rs * lw[i0 + 3] + lb[i0 + 3]);
    orow[i1 + 0] = f2bfu((v1.x - mu) * rs * lw[i1 + 0] + lb[i1 + 0]);
    orow[i1 + 1] = f2bfu((v1.y - mu) * rs * lw[i1 + 1] + lb[i1 + 1]);
    orow[i1 + 2] = f2bfu((v1.z - mu) * rs * lw[i1 + 2] + lb[i1 + 2]);
    orow[i1 + 3] = f2bfu((v1.w - mu) * rs * lw[i1 + 3] + lb[i1 + 3]);
}

// ---------------- WO combine + residual + LN2, one block per row ----------------
__global__ __launch_bounds__(256)
void wo_ln(const unsigned short* __restrict__ part, const float* __restrict__ h,
           const float* __restrict__ bo, const float* __restrict__ w,
           const float* __restrict__ b, float* __restrict__ out,
           unsigned short* __restrict__ ybf) {
    const int row = blockIdx.x;
    const int tid = threadIdx.x;
    const int c0 = tid * 4, c1 = (tid + 256) * 4;
    float4 o0 = ((const float4*)(h + (size_t)row * HIDN))[tid];
    float4 o1 = ((const float4*)(h + (size_t)row * HIDN))[tid + 256];
    o0.x += bo[c0]; o0.y += bo[c0 + 1]; o0.z += bo[c0 + 2]; o0.w += bo[c0 + 3];
    o1.x += bo[c1]; o1.y += bo[c1 + 1]; o1.z += bo[c1 + 2]; o1.w += bo[c1 + 3];
#pragma unroll
    for (int sk = 0; sk < 4; ++sk) {
        const unsigned short* pr = part + (size_t)sk * 4194304 + (size_t)row * HIDN;
        u16x4 p0 = *(const u16x4*)(pr + c0);
        u16x4 p1 = *(const u16x4*)(pr + c1);
        o0.x += bfu2f(p0[0]); o0.y += bfu2f(p0[1]); o0.z += bfu2f(p0[2]); o0.w += bfu2f(p0[3]);
        o1.x += bfu2f(p1[0]); o1.y += bfu2f(p1[1]); o1.z += bfu2f(p1[2]); o1.w += bfu2f(p1[3]);
    }
    ((float4*)(out + (size_t)row * HIDN))[tid] = o0;
    ((float4*)(out + (size_t)row * HIDN))[tid + 256] = o1;
    float s = o0.x + o0.y + o0.z + o0.w + o1.x + o1.y + o1.z + o1.w;
    float q = o0.x*o0.x + o0.y*o0.y + o0.z*o0.z + o0.w*o0.w
            + o1.x*o1.x + o1.y*o1.y + o1.z*o1.z + o1.w*o1.w;
    for (int o = 32; o > 0; o >>= 1) {
        s += __shfl_down(s, o, 64);
        q += __shfl_down(q, o, 64);
    }
    __shared__ float red[8];
    const int wid = tid >> 6;
    if ((tid & 63) == 0) { red[wid] = s; red[4 + wid] = q; }
    __syncthreads();
    float st = red[0] + red[1] + red[2] + red[3];
    float qt = red[4] + red[5] + red[6] + red[7];
    float mu = st * (1.0f / HIDN);
    float var = qt * (1.0f / HIDN) - mu * mu;
    float rs = rsqrtf(var + 1e-5f);
    unsigned short* yr = ybf + (size_t)row * HIDN;
    yr[c0 + 0] = f2bfu((o0.x - mu) * rs * w[c0 + 0] + b[c0 + 0]);
    yr[c0 + 1] = f2bfu((o0.y - mu) * rs * w[c0 + 1] + b[c0 + 1]);
    yr[c0 + 2] = f2bfu((o0.z - mu) * rs * w[c0 + 2] + b[c0 + 2]);
    yr[c0 + 3] = f2bfu((o0.w - mu) * rs * w[c0 + 3] + b[c0 + 3]);
    yr[c1 + 0] = f2bfu((o1.x - mu) * rs * w[c1 + 0] + b[c1 + 0]);
    yr[c1 + 1] = f2bfu((o1.y - mu) * rs * w[c1 + 1] + b[c1 + 1]);
    yr[c1 + 2] = f2bfu((o1.z - mu) * rs * w[c1 + 2] + b[c1 + 2]);
    yr[c1 + 3] = f2bfu((o1.w - mu) * rs * w[c1 + 3] + b[c1 + 3]);
}

// ---------------- RoPE in-place on qk buffer [S][4096] ----------------
__global__ __launch_bounds__(256)
void rope_kernel(unsigned short* __restrict__ qk, const int* __restrict__ tsl) {
    int id = blockIdx.x * 256 + threadIdx.x;
    int p  = id & 63;
    int hh = (id >> 6) & 31;
    int s  = id >> 11;
    int off = tsl[0] - SEQLEN;
    float inv = exp2f((float)p * -0.20762050593f);
    float ang = (float)(s + off) * inv;
    float c, sn;
    __sincosf(ang, &sn, &c);
    size_t base = (size_t)s * 4096 + hh * 128 + p;
    float x1 = bfu2f(qk[base]);
    float x2 = bfu2f(qk[base + 64]);
    qk[base]      = f2bfu(x1 * c - x2 * sn);
    qk[base + 64] = f2bfu(x2 * c + x1 * sn);
}

// ======= 256x256 8-phase GEMM (R8 schedule) + dual-source tail-conv blocks =======
#define BAR __builtin_amdgcn_s_barrier()
#define VM4 asm volatile("s_waitcnt vmcnt(4)" ::: "memory")
#define VM0 asm volatile("s_waitcnt vmcnt(0)" ::: "memory")

#define STAGE_A(tile, h) { const int k0_ = k_start + (tile) * 64;                      \
  _Pragma("unroll") for (int i_ = 0; i_ < 2; ++i_) {                                   \
    int d_ = (h) * 16384 + i_ * 8192 + tid * 16;                                       \
    int r_ = d_ >> 7;                                                                  \
    int cb_ = (d_ & 127) ^ ((r_ & 7) << 4);                                            \
    gload16((const char*)Ab + ((size_t)(brow + r_) * lda + k0_) * 2 + cb_,             \
            smem + ((tile) & 1) * 65536 + (h) * 16384 + i_ * 8192 + w * 1024); } }

#define STAGE_B(tile, h) { const int k0_ = k_start + (tile) * 64;                      \
  _Pragma("unroll") for (int i_ = 0; i_ < 2; ++i_) {                                   \
    int d_ = (h) * 16384 + i_ * 8192 + tid * 16;                                       \
    int r_ = d_ >> 7;                                                                  \
    int cb_ = (d_ & 127) ^ ((r_ & 7) << 4);                                            \
    gload16((const char*)Bb + ((size_t)(bcol + r_) * ldb + k0_) * 2 + cb_,             \
            smem + ((tile) & 1) * 65536 + 32768 + (h) * 16384 + i_ * 8192 + w * 1024); } }

#define LDB(BO)                                                                        \
  _Pragma("unroll") for (int n_ = 0; n_ < 4; ++n_)                                     \
  _Pragma("unroll") for (int kk_ = 0; kk_ < 2; ++kk_)                                  \
    bF[n_][kk_] = *(const bf16x8*)(smem + (BO) + bbase + n_ * 2048 + colb[kk_]);

#define LDA2(BO, MP)                                                                   \
  _Pragma("unroll") for (int dm_ = 0; dm_ < 2; ++dm_)                                  \
  _Pragma("unroll") for (int kk_ = 0; kk_ < 2; ++kk_)                                  \
    aF[dm_][kk_] = *(const bf16x8*)(smem + (BO) + abase + ((MP) * 2 + dm_) * 2048 + colb[kk_]);

#define MM(MP)                                                                         \
  __builtin_amdgcn_s_setprio(1);                                                       \
  _Pragma("unroll") for (int dm_ = 0; dm_ < 2; ++dm_)                                  \
  _Pragma("unroll") for (int n_ = 0; n_ < 4; ++n_)                                     \
  _Pragma("unroll") for (int kk_ = 0; kk_ < 2; ++kk_)                                  \
    acc[(MP) * 2 + dm_][n_] = __builtin_amdgcn_mfma_f32_16x16x32_bf16(                 \
        aF[dm_][kk_], bF[n_][kk_], acc[(MP) * 2 + dm_][n_], 0, 0, 0);                  \
  __builtin_amdgcn_s_setprio(0);

template<int EPI>
__global__ __launch_bounds__(512, 1)
void gemm256(const unsigned short* __restrict__ Ab, int lda,
             const unsigned short* __restrict__ Bb, int ldb,
             int k_len, int nbx, int ldc,
             const float* __restrict__ bias0, const float* __restrict__ bias1,
             const float* __restrict__ bias2,
             unsigned short* __restrict__ outB, unsigned short* __restrict__ outV,
             int ngemm,
             const float* __restrict__ csA, unsigned short* __restrict__ cdA, int n8A,
             const float* __restrict__ csB, unsigned short* __restrict__ cdB, int n8B) {
    extern __shared__ char smem[];   // 131072 bytes
    const int tid = threadIdx.x;

    if ((int)blockIdx.x >= ngemm) {
        if (blockIdx.y == 0) {
            const int nconv = gridDim.x - ngemm;
            conv_two(csA, cdA, n8A, csB, cdB, n8B,
                     (blockIdx.x - ngemm) * 512 + tid, nconv * 512);
        }
        return;
    }

    const int w = tid >> 6, lane = tid & 63;
    const int lr = lane & 15, lg = lane >> 4;
    const int wrow = (w >> 2) * 128;
    const int wc = w & 3;

    const int cpx = nbx >> 3;
    const int xcd = blockIdx.x & 7;
    const int loc = blockIdx.x >> 3;
    const int bx = xcd * cpx + loc % cpx;
    const int by = loc / cpx;
    const int brow = by * 256, bcol = bx * 256;
    const int k_start = blockIdx.y * k_len;

    const int xorv = (lr & 7) << 4;
    int colb[2];
    colb[0] = (lg * 16) ^ xorv;
    colb[1] = (64 + lg * 16) ^ xorv;
    const int abase = (wrow + lr) * 128;
    const int bbase = 32768 + (wc * 64 + lr) * 128;

    f32x4 acc[8][4];
#pragma unroll
    for (int m = 0; m < 8; ++m)
#pragma unroll
        for (int n = 0; n < 4; ++n) acc[m][n] = (f32x4){0.f, 0.f, 0.f, 0.f};

    bf16x8 bF[4][2], aF[2][2];

    const int NT = k_len >> 6;
    const int NIT = NT >> 1;

    STAGE_A(0, 0); STAGE_A(0, 1); STAGE_B(0, 0); STAGE_B(0, 1);
    STAGE_B(1, 0); STAGE_B(1, 1);
    VM4; BAR;

    for (int it = 0; it < NIT; ++it) {
        const int T = 2 * it;
        const bool s2 = (T + 2) < NT, s3 = (T + 3) < NT;
        LDB(0); LDA2(0, 0); STAGE_A(T + 1, 0); MM(0); BAR;
        LDA2(0, 1); STAGE_A(T + 1, 1); MM(1); BAR;
        LDA2(0, 2); if (s2) STAGE_B(T + 2, 0); MM(2); BAR;
        LDA2(0, 3); if (s2) STAGE_B(T + 2, 1); MM(3);
        if (s2) { VM4; } else { VM0; }
        BAR;
        LDB(65536); LDA2(65536, 0); if (s2) STAGE_A(T + 2, 0); MM(0); BAR;
        LDA2(65536, 1); if (s2) STAGE_A(T + 2, 1); MM(1); BAR;
        LDA2(65536, 2); if (s3) STAGE_B(T + 3, 0); MM(2); BAR;
        LDA2(65536, 3); if (s3) STAGE_B(T + 3, 1); MM(3);
        if (s3) { VM4; } else { VM0; }
        BAR;
    }

    // ======== LDS-staged epilogue ========
    char* sw = smem + w * 16384;
    const bool vblk = (EPI == 0) && (bcol >= 4096);

    if (!vblk) {
#pragma unroll
        for (int n = 0; n < 4; ++n) {
            const int col = bcol + wc * 64 + n * 16 + lr;
            float bv = 0.f;
            if (EPI == 0) bv = (col < 2048) ? bias0[col] : bias1[col - 2048];
#pragma unroll
            for (int m = 0; m < 8; ++m)
#pragma unroll
                for (int j = 0; j < 4; ++j) {
                    const int r = m * 16 + lg * 4 + j;
                    const int cb = ((n * 16 + lr) * 2) ^ ((r & 7) << 4);
                    *(unsigned short*)(sw + r * 128 + cb) = f2bfu(acc[m][n][j] + bv);
                }
        }
        const int rl = lane >> 3, cl = lane & 7;
#pragma unroll
        for (int it2 = 0; it2 < 16; ++it2) {
            const int r = it2 * 8 + rl;
            const int cb = (cl * 16) ^ ((r & 7) << 4);
            u16x8 val = *(const u16x8*)(sw + r * 128 + cb);
            const int gr = brow + wrow + r;
            const int gcol = bcol + wc * 64 + cl * 8;
            if (EPI == 0) {
                *(u16x8*)(outB + (size_t)gr * 4096 + gcol) = val;
            } else if (EPI == 1) {
                *(u16x8*)(outB + (size_t)gr * ldc + gcol) = val;
            } else if (EPI == 3) {
                unsigned short* gp = outB + (size_t)gr * ldc + gcol;
                u16x8 gv = *(const u16x8*)gp;
                u16x8 ov;
#pragma unroll
                for (int e = 0; e < 8; ++e) {
                    float g = bfu2f(gv[e]);
                    float uu = bfu2f(val[e]);
                    ov[e] = f2bfu(g / (1.0f + __expf(-g)) * uu);
                }
                *(u16x8*)gp = ov;
            } else {
                *(u16x8*)(outB + (size_t)blockIdx.y * 4194304 + (size_t)gr * ldc + gcol) = val;
            }
        }
    } else {
#pragma unroll
        for (int n = 0; n < 4; ++n) {
            const int c = n * 16 + lr;
            const float bv = bias2[bcol - 4096 + wc * 64 + c];
            const int cx = (c & 7) << 4;
#pragma unroll
            for (int m = 0; m < 8; ++m) {
                const int r0 = m * 16 + lg * 4;
                u16x4 pk;
#pragma unroll
                for (int j = 0; j < 4; ++j) pk[j] = f2bfu(acc[m][n][j] + bv);
                *(u16x4*)(sw + c * 256 + ((r0 * 2) ^ cx)) = pk;
            }
        }
        const int cg = lane >> 4, rl2 = lane & 15;
#pragma unroll
        for (int it2 = 0; it2 < 16; ++it2) {
            const int c = it2 * 4 + cg;
            const int rb = (rl2 * 16) ^ ((c & 7) << 4);
            u16x8 val = *(const u16x8*)(sw + c * 256 + rb);
            const int d = bcol - 4096 + wc * 64 + c;
            *(u16x8*)(outV + (size_t)d * SEQLEN + brow + wrow + rl2 * 8) = val;
        }
    }
}

// ---------------- split-K reduce: out += sum of 4 bf16 partials ----------------
__global__ __launch_bounds__(256)
void reduce4_add(const unsigned short* __restrict__ part, float* __restrict__ out) {
    int i = blockIdx.x * 256 + threadIdx.x;
    float4 o = ((const float4*)out)[i];
#pragma unroll
    for (int sk = 0; sk < 4; ++sk) {
        u16x4 p = ((const u16x4*)(part + (size_t)sk * 4194304))[i];
        o.x += bfu2f(p[0]); o.y += bfu2f(p[1]); o.z += bfu2f(p[2]); o.w += bfu2f(p[3]);
    }
    ((float4*)out)[i] = o;
}

// ---- Flash attention: static-max exp2 softmax, l via ones-MFMA, ranged conv riders ----
#define PST 72
__global__ __launch_bounds__(256)
void attn_kernel(const unsigned short* __restrict__ QK, const unsigned short* __restrict__ VT,
                 unsigned short* __restrict__ O,
                 const float* __restrict__ c0, const float* __restrict__ c1,
                 const float* __restrict__ c2, unsigned short* __restrict__ cdst,
                 int cstart, int cend) {
    __shared__ __align__(16) unsigned short Ks[2][64 * 128];
    __shared__ __align__(16) unsigned short Vs[2][128 * 64];
    __shared__ __align__(16) unsigned short Ps[4][16 * PST];
    const int tid = threadIdx.x;

    if ((int)blockIdx.x >= 256) {
        const int nconv = gridDim.x - 256;
        conv_tail_rng(c0, c1, c2, cdst, (blockIdx.x - 256) * 256 + tid, nconv * 256,
                      cstart, cend);
        return;
    }

    const int lane = tid & 63;
    const int w = tid >> 6;
    const int lr = lane & 15, lg = lane >> 4;

    const int id = blockIdx.x;
    const int h = ((id & 7) << 1) | ((id >> 3) & 1);
    const int p = id >> 4;

    const unsigned short* Kb = QK + 2048 + h * 128;
    const unsigned short* Vb = VT + (size_t)(h * 128) * SEQLEN;

    int krow[4], kcb[4], vrow[4], vcb[4];
#pragma unroll
    for (int ch = 0; ch < 4; ++ch) {
        int d = ch * 4096 + w * 1024 + lane * 16;
        krow[ch] = d >> 8;
        kcb[ch]  = (d & 255) ^ ((krow[ch] & 7) << 4);
        vrow[ch] = d >> 7;
        vcb[ch]  = (d & 127) ^ ((vrow[ch] & 7) << 4);
    }

    const float sc2 = 0.08838834764831845f * 1.44269504089f;
    bf16x8 ones;
#pragma unroll
    for (int e = 0; e < 8; ++e) ones[e] = (__bf16)1.0f;

#pragma unroll 1
    for (int seg = 0; seg < 2; ++seg) {
        const int qb = seg ? (31 - p) : p;
        const int qw = qb * 64 + w * 16;
        const unsigned short* Qb = QK + (size_t)qw * 4096 + h * 128;

        bf16x8 qa[4];
#pragma unroll
        for (int c = 0; c < 4; ++c)
            qa[c] = *(const bf16x8*)(Qb + (size_t)lr * 4096 + c * 32 + lg * 8);

        f32x4 acc[8];
#pragma unroll
        for (int dt = 0; dt < 8; ++dt) acc[dt] = (f32x4){0.f, 0.f, 0.f, 0.f};
        f32x4 lacc = (f32x4){0.f, 0.f, 0.f, 0.f};
        const int ntile = qb + 1;

#pragma unroll
        for (int ch = 0; ch < 4; ++ch) {
            gload16(Kb + (size_t)krow[ch] * 4096 + (kcb[ch] >> 1),
                    (char*)&Ks[0][0] + ch * 4096 + w * 1024);
            gload16(Vb + (size_t)vrow[ch] * SEQLEN + (vcb[ch] >> 1),
                    (char*)&Vs[0][0] + ch * 4096 + w * 1024);
        }
        __syncthreads();

        for (int tt = 0; tt < ntile; ++tt) {
            const int cur = tt & 1;
            const int t0 = tt * 64;
            if (tt + 1 < ntile) {
                const int t1 = t0 + 64;
#pragma unroll
                for (int ch = 0; ch < 4; ++ch) {
                    gload16(Kb + (size_t)(t1 + krow[ch]) * 4096 + (kcb[ch] >> 1),
                            (char*)&Ks[cur ^ 1][0] + ch * 4096 + w * 1024);
                    gload16(Vb + (size_t)vrow[ch] * SEQLEN + t1 + (vcb[ch] >> 1),
                            (char*)&Vs[cur ^ 1][0] + ch * 4096 + w * 1024);
                }
            }
            f32x4 s[4];
#pragma unroll
            for (int th = 0; th < 4; ++th) s[th] = (f32x4){0.f, 0.f, 0.f, 0.f};
            __builtin_amdgcn_s_setprio(1);
#pragma unroll
            for (int th = 0; th < 4; ++th) {
                const int row = th * 16 + lr;
#pragma unroll
                for (int c = 0; c < 4; ++c) {
                    bf16x8 kb = *(const bf16x8*)((char*)&Ks[cur][0] + row * 256 +
                                                 ((c * 64 + lg * 16) ^ ((lr & 7) << 4)));
                    s[th] = __builtin_amdgcn_mfma_f32_16x16x32_bf16(qa[c], kb, s[th], 0, 0, 0);
                }
            }
            __builtin_amdgcn_s_setprio(0);
            if (tt == qb) {
#pragma unroll
                for (int th = 0; th < 4; ++th) {
                    int tg = t0 + th * 16 + lr;
#pragma unroll
                    for (int jj = 0; jj < 4; ++jj) {
                        int qg = qw + lg * 4 + jj;
                        float v = s[th][jj] * sc2 + (tg <= qg ? 0.f : -1e9f);
                        s[th][jj] = exp2f(v);
                    }
                }
            } else {
#pragma unroll
                for (int th = 0; th < 4; ++th)
#pragma unroll
                    for (int jj = 0; jj < 4; ++jj)
                        s[th][jj] = exp2f(s[th][jj] * sc2);
            }
#pragma unroll
            for (int th = 0; th < 4; ++th)
#pragma unroll
                for (int jj = 0; jj < 4; ++jj)
                    Ps[w][(lg * 4 + jj) * PST + th * 16 + lr] = f2bfu(s[th][jj]);
            bf16x8 pa[2];
#pragma unroll
            for (int ks = 0; ks < 2; ++ks)
                pa[ks] = *(const bf16x8*)&Ps[w][lr * PST + ks * 32 + lg * 8];
            __builtin_amdgcn_s_setprio(1);
            lacc = __builtin_amdgcn_mfma_f32_16x16x32_bf16(pa[0], ones, lacc, 0, 0, 0);
            lacc = __builtin_amdgcn_mfma_f32_16x16x32_bf16(pa[1], ones, lacc, 0, 0, 0);
#pragma unroll
            for (int dt = 0; dt < 8; ++dt) {
                const int d = dt * 16 + lr;
#pragma unroll
                for (int ks = 0; ks < 2; ++ks) {
                    bf16x8 vb = *(const bf16x8*)((char*)&Vs[cur][0] + d * 128 +
                                                 ((ks * 64 + lg * 16) ^ ((lr & 7) << 4)));
                    acc[dt] = __builtin_amdgcn_mfma_f32_16x16x32_bf16(pa[ks], vb, acc[dt], 0, 0, 0);
                }
            }
            __builtin_amdgcn_s_setprio(0);
            __syncthreads();
        }
        float invl[4];
#pragma unroll
        for (int jj = 0; jj < 4; ++jj) invl[jj] = 1.0f / lacc[jj];
#pragma unroll
        for (int dt = 0; dt < 8; ++dt)
#pragma unroll
            for (int jj = 0; jj < 4; ++jj)
                O[(size_t)(qw + lg * 4 + jj) * HIDN + h * HDIM + dt * 16 + lr] =
                    f2bfu(acc[dt][jj] * invl[jj]);
    }
}

extern "C" void kernel_launch(void* const* d_in, const int* in_sizes, int n_in,
                              void* d_out, int out_size, void* d_ws, size_t ws_size,
                              hipStream_t stream) {
    const float* hidden = (const float*)d_in[0];
    const float* ln1w = (const float*)d_in[2];
    const float* ln1b = (const float*)d_in[3];
    const float* ln2w = (const float*)d_in[4];
    const float* ln2b = (const float*)d_in[5];
    const float* wq = (const float*)d_in[6];
    const float* bq = (const float*)d_in[7];
    const float* wk = (const float*)d_in[8];
    const float* bk = (const float*)d_in[9];
    const float* wv = (const float*)d_in[10];
    const float* bv = (const float*)d_in[11];
    const float* wo = (const float*)d_in[12];
    const float* bo = (const float*)d_in[13];
    const float* wg = (const float*)d_in[14];
    const float* wu = (const float*)d_in[15];
    const float* wd = (const float*)d_in[16];
    const int* tsl = (const int*)d_in[17];
    float* out = (float*)d_out;

    char* ws = (char*)d_ws;
    const size_t MB = 1024 * 1024;
    unsigned short* Wbuf = (unsigned short*)(ws);            // 32 MiB: qkv(24) + wo(8)
    unsigned short* qk   = (unsigned short*)(ws + 32 * MB);  // 16 MiB
    unsigned short* vt   = (unsigned short*)(ws + 48 * MB);  // 8 MiB
    unsigned short* x_bf = (unsigned short*)(ws + 56 * MB);  // 8 MiB; attn out reuses
    unsigned short* g_bf = (unsigned short*)(ws + 64 * MB);  // 32 MiB; WO partials reuse
    unsigned short* part = qk;                               // 32 MiB for down partials
    unsigned short* y_bf = vt;

    const int HID2 = HIDN * HIDN;
    const int FFE  = FFDIM * HIDN;
    const int FF8  = FFE / 8;                 // 2097152
    const int CONV_FF = FF8 / 256;
    const size_t LDSZ = 131072;

    int nmat = 0;
    if (ws_size >= 192 * MB) nmat = 3;
    else if (ws_size >= 160 * MB) nmat = 2;
    else if (ws_size >= 128 * MB) nmat = 1;
    unsigned short* wgBuf = (nmat > 0) ? (unsigned short*)(ws + 96 * MB) : Wbuf;
    unsigned short* wuBuf = (nmat > 1) ? wgBuf + (size_t)FFE : Wbuf;
    unsigned short* wdBuf = (nmat > 2) ? wgBuf + 2 * (size_t)FFE : Wbuf;

    // split wg: first SKIP groups on QKV riders, rest on attn riders
    const int SKIP = (nmat >= 1) ? (FF8 * 5) / 8 : 0;   // 1310720

    // ---- fused prep: convert wq/wk/wv + LN1 in one launch ----
    prep_qkv<<<6144 + 2048, 256, 0, stream>>>(wq, wk, wv, Wbuf,
                                              hidden, ln1w, ln1b, x_bf);

    // ---- QKV GEMM; riders convert wo + first 5/8 of wg ----
    gemm256<0><<<dim3(192 + 64, 1), 512, LDSZ, stream>>>(
        x_bf, HIDN, Wbuf, HIDN, HIDN, 24, 0, bq, bk, bv, qk, vt,
        192,
        wo, Wbuf + 3 * (size_t)HID2, HID2 / 8,
        wg, wgBuf, SKIP);
    rope_kernel<<<SEQLEN * 32 * 64 / 256, 256, 0, stream>>>(qk, tsl);

    // ---- attention; riders convert rest of wg + wu + wd (range [SKIP, nmat*FF8)) ----
    if (nmat > 0) {
        attn_kernel<<<768, 256, 0, stream>>>(qk, vt, x_bf, wg, wu, wd, wgBuf,
                                             SKIP, nmat * FF8);
    } else {
        attn_kernel<<<256, 256, 0, stream>>>(qk, vt, x_bf, nullptr, nullptr, nullptr,
                                             nullptr, 0, 0);
    }

    // ---- WO + residual + LN2 ----
    gemm256<4><<<dim3(64, 4), 512, LDSZ, stream>>>(
        x_bf, HIDN, Wbuf + 3 * (size_t)HID2, HIDN, 512, 8, HIDN,
        nullptr, nullptr, nullptr, g_bf, nullptr, 64,
        nullptr, nullptr, 0, nullptr, nullptr, 0);
    wo_ln<<<SEQLEN, 256, 0, stream>>>(g_bf, hidden, bo, ln2w, ln2b, out, y_bf);

    // ---- FFN ----
    if (nmat < 1) conv_f32_bf16<<<CONV_FF, 256, 0, stream>>>(wg, Wbuf);
    gemm256<1><<<dim3(256, 1), 512, LDSZ, stream>>>(
        y_bf, HIDN, wgBuf, HIDN, HIDN, 32, FFDIM,
        nullptr, nullptr, nullptr, g_bf, nullptr, 256,
        nullptr, nullptr, 0, nullptr, nullptr, 0);
    if (nmat < 2) conv_f32_bf16<<<CONV_FF, 256, 0, stream>>>(wu, Wbuf);
    gemm256<3><<<dim3(256, 1), 512, LDSZ, stream>>>(
        y_bf, HIDN, wuBuf, HIDN, HIDN, 32, FFDIM,
        nullptr, nullptr, nullptr, g_bf, nullptr, 256,
        nullptr, nullptr, 0, nullptr, nullptr, 0);
    if (nmat < 3) conv_f32_bf16<<<CONV_FF, 256, 0, stream>>>(wd, Wbuf);
    gemm256<4><<<dim3(64, 4), 512, LDSZ, stream>>>(
        g_bf, FFDIM, wdBuf, FFDIM, 2048, 8, HIDN,
        nullptr, nullptr, nullptr, part, nullptr, 64,
        nullptr, nullptr, 0, nullptr, nullptr, 0);
    reduce4_add<<<4096, 256, 0, stream>>>(part, out);
}